// Round 1
// baseline (240.659 us; speedup 1.0000x reference)
//
#include <hip/hip_runtime.h>
#include <hip/hip_bf16.h>
#include <math.h>

#define BB 2
#define SS 2048
#define DMM 1024
#define HH 16
#define HDD 64
#define NGLOB 32
#define MM 4096   // B*S
#define SCALE2 0.18033688f   // 0.125 * log2(e): exp(s/8) == exp2(s*SCALE2)

typedef __attribute__((ext_vector_type(8))) short short8;
typedef __attribute__((ext_vector_type(4))) float float4v;

__device__ __forceinline__ short f2bf(float f) {
    union { float f; unsigned u; } x; x.f = f;
    unsigned r = (x.u + 0x7fffu + ((x.u >> 16) & 1u)) >> 16;  // RNE
    return (short)r;
}

// async 16B global->LDS (m97 path). LDS dest = wave-uniform base + lane*16.
#define ASYNC16(gp, lp) __builtin_amdgcn_global_load_lds( \
    (__attribute__((address_space(1))) void*)(gp), \
    (__attribute__((address_space(3))) void*)(lp), 16, 0, 0)

// Vt slot swizzle: key-chunk XORed with dim-derived tag -> breaks the
// dim*stride==0 (mod 32 banks) collapse on transpose stores (16-way -> 4-way).
#define VSL(dim, key) ((dim) * 40 + (((((key) >> 3) ^ (((dim) >> 3) & 3)) << 3) | ((key) & 7)))

// ---------------- setup: parallel dedup'd global list (order irrelevant) ----------------
__global__ void setup_globals(const int* __restrict__ gidx, int* __restrict__ g,
                              int* __restrict__ glist, int* __restrict__ gcount) {
    int t = threadIdx.x;
    for (int i = t; i < SS; i += 256) g[i] = 0;
    if (t == 0) *gcount = 0;
    __syncthreads();
    if (t < NGLOB) {
        int j = gidx[t];
        if (j >= 0 && j < SS) g[j] = 1;
    }
    __syncthreads();
    for (int j = t; j < SS; j += 256) {
        if (g[j]) {
            int p = atomicAdd(gcount, 1);
            glist[p] = j;
        }
    }
}

// ---------------- convert inputs q,k,v (4M ea) + 4 weights (1M ea) fp32 -> bf16 ----------------
__global__ __launch_bounds__(256)
void convert_all(const float* __restrict__ q, const float* __restrict__ k,
                 const float* __restrict__ v,
                 const float* __restrict__ w0, const float* __restrict__ w1,
                 const float* __restrict__ w2, const float* __restrict__ w3,
                 short* __restrict__ abf, short* __restrict__ wbf) {
    int z = blockIdx.y;
    const float* src;
    short* dst;
    size_t n;
    if (z < 3) {
        src = (z == 0) ? q : (z == 1) ? k : v;
        dst = abf + (size_t)z * ((size_t)MM * DMM);
        n = (size_t)MM * DMM;
    } else {
        int y = z - 3;
        src = (y == 0) ? w0 : (y == 1) ? w1 : (y == 2) ? w2 : w3;
        dst = wbf + (size_t)y * ((size_t)DMM * DMM);
        n = (size_t)DMM * DMM;
    }
    size_t i = ((size_t)blockIdx.x * 256 + threadIdx.x) * 8;
    if (i >= n) return;
    float4 a = *(const float4*)(src + i);
    float4 b = *(const float4*)(src + i + 4);
    short8 s;
    s[0]=f2bf(a.x); s[1]=f2bf(a.y); s[2]=f2bf(a.z); s[3]=f2bf(a.w);
    s[4]=f2bf(b.x); s[5]=f2bf(b.y); s[6]=f2bf(b.z); s[7]=f2bf(b.w);
    *(short8*)(dst + i) = s;
}

// ---------------- m97-style MFMA GEMM, 128x128 tile (4 waves x 64x64, acc[4][4]) ----------------
// 32 FLOP per LDS byte read (vs 21.8 at 64x128): per wave K-step 16 MFMA vs 8 ds_read_b128.
template<int OBF, int HEADSPLIT>
__global__ __launch_bounds__(256)
void gemm128(const short* __restrict__ Abase, const short* __restrict__ Wbase,
             const float* __restrict__ b0, const float* __restrict__ b1,
             const float* __restrict__ b2,
             void* __restrict__ O0p, void* __restrict__ O1p, void* __restrict__ O2p) {
    __shared__ short As[128 * 32];   // 8 KB
    __shared__ short Ws[128 * 32];   // 8 KB

    int t = threadIdx.x;
    int z = blockIdx.y;
    const short* A    = Abase + (size_t)z * ((size_t)MM * DMM);
    const short* W    = Wbase + (size_t)z * ((size_t)DMM * DMM);
    const float* bias = (z == 0) ? b0 : (z == 1) ? b1 : b2;
    void* outp        = (z == 0) ? O0p : (z == 1) ? O1p : O2p;

    int bid = blockIdx.x;
    int xcd = bid & 7, loc = bid >> 3;     // XCD round-robin, 32 blocks/XCD
    int nblk = loc & 7, mloc = loc >> 3;   // per-XCD: 4 m-blocks x 8 n-blocks
    int m0 = (xcd * 4 + mloc) * 128;       // A-panel/XCD 1MB + B-panel 2MB fits 4MB L2
    int n0 = nblk * 128;

    int lane = t & 63, w = t >> 6;
    int quad = lane >> 4, col = lane & 15;
    int wr = (w & 1) * 64;    // wave's 64x64 quadrant
    int wc = (w >> 1) * 64;

    float4v acc[4][4];
    #pragma unroll
    for (int i = 0; i < 4; i++)
        #pragma unroll
        for (int j = 0; j < 4; j++) acc[i][j] = (float4v){0, 0, 0, 0};

    int rowA = t >> 2,  kcA = (t & 3) * 8;

    for (int it = 0; it < 32; it++) {
        int k0 = it * 32;
        ASYNC16(A + (size_t)(m0 + rowA) * DMM + k0 + kcA,      &As[t * 8]);
        ASYNC16(A + (size_t)(m0 + 64 + rowA) * DMM + k0 + kcA, &As[2048 + t * 8]);
        ASYNC16(W + (size_t)(n0 + rowA) * DMM + k0 + kcA,      &Ws[t * 8]);
        ASYNC16(W + (size_t)(n0 + 64 + rowA) * DMM + k0 + kcA, &Ws[2048 + t * 8]);
        __syncthreads();

        short8 aF[4], bF[4];
        #pragma unroll
        for (int i = 0; i < 4; i++)
            aF[i] = *(short8*)&As[(wr + 16 * i + col) * 32 + quad * 8];
        #pragma unroll
        for (int j = 0; j < 4; j++)
            bF[j] = *(short8*)&Ws[(wc + 16 * j + col) * 32 + quad * 8];

        #pragma unroll
        for (int i = 0; i < 4; i++)
            #pragma unroll
            for (int j = 0; j < 4; j++)
                acc[i][j] = __builtin_amdgcn_mfma_f32_16x16x32_bf16(aF[i], bF[j], acc[i][j], 0, 0, 0);
        __syncthreads();
    }

    #pragma unroll
    for (int i = 0; i < 4; i++) {
        #pragma unroll
        for (int j = 0; j < 4; j++) {
            int n = n0 + wc + 16 * j + col;
            float bn = bias[n];
            #pragma unroll
            for (int r = 0; r < 4; r++) {
                int m = m0 + wr + 16 * i + quad * 4 + r;
                float val = acc[i][j][r] + bn;
                size_t idx;
                if (HEADSPLIT) {
                    int b = m >> 11;
                    int s = m & 2047;
                    int h = n >> 6;
                    int hd = n & 63;
                    idx = (((size_t)b * HH + h) * SS + s) * HDD + hd;
                } else {
                    idx = (size_t)m * DMM + n;
                }
                if (OBF) ((short*)outp)[idx] = f2bf(val);
                else     ((float*)outp)[idx] = val;
            }
        }
    }
}

// ---------------- banded MFMA attention (XCD-local, swizzled Vt, interval mask) ----------------
// 1D grid 1024: all 16 q-tiles of a (b,h,parity) group land on one XCD (L2 reuse).
__global__ __launch_bounds__(256)
void band_attn(const short* __restrict__ qh, const short* __restrict__ kh,
               const short* __restrict__ vh, const int* __restrict__ glist,
               const int* __restrict__ gcount, short* __restrict__ ao) {
    __shared__ short Qs[64 * 72];
    __shared__ short Ks[32 * 72];
    __shared__ short Vt[64 * 40];
    __shared__ short Ps[4 * 16 * 40];
    __shared__ int   gjs[32];

    int t = threadIdx.x;
    int bid = blockIdx.x;
    int xcd = bid & 7, idx = bid >> 3;
    int gl  = idx >> 4;             // 0..7: group slot within XCD
    int qt  = idx & 15;             // q-tile
    int gid = xcd * 8 + gl;         // 0..63 -> (z,h)
    int z   = gid >> 4;
    int h   = gid & 15;
    int b = z >> 1, p = z & 1;
    int qq0 = qt * 64;
    int nG = *gcount;

    const short* Qb = qh + ((size_t)(b * HH + h) * SS) * HDD;
    const short* Kb = kh + ((size_t)(b * HH + h) * SS) * HDD;
    const short* Vb = vh + ((size_t)(b * HH + h) * SS) * HDD;

    int row8 = t >> 3;
    int dim8 = (t & 7) * 8;

    #pragma unroll
    for (int rr = 0; rr < 2; rr++) {
        int row = rr * 32 + row8;
        int i = 2 * (qq0 + row) + p;
        short8 qv = *(const short8*)(Qb + (size_t)i * HDD + dim8);
        *(short8*)&Qs[row * 72 + dim8] = qv;
    }
    if (t < 32) gjs[t] = (t < nG) ? glist[t] : -1000000;
    __syncthreads();

    int lane = t & 63, w = t >> 6;
    int quad = lane >> 4, col = lane & 15;

    short8 qf0 = *(short8*)&Qs[(16 * w + col) * 72 + quad * 8];
    short8 qf1 = *(short8*)&Qs[(16 * w + col) * 72 + 32 + quad * 8];

    float4v O0 = {0,0,0,0}, O1 = {0,0,0,0}, O2 = {0,0,0,0}, O3 = {0,0,0,0};
    float lst[4] = {0.f, 0.f, 0.f, 0.f};

    for (int c = 0; c < 19; c++) {
        __syncthreads();
        int ch0 = qq0 - 256 + c * 32;
        int srow;
        if (c < 18) srow = 2 * (ch0 + row8) + p;
        else        srow = (row8 < nG) ? gjs[row8] : 0;
        srow = srow < 0 ? 0 : (srow > SS - 1 ? SS - 1 : srow);
        short8 kv = *(const short8*)(Kb + (size_t)srow * HDD + dim8);
        short8 vv = *(const short8*)(Vb + (size_t)srow * HDD + dim8);
        *(short8*)&Ks[row8 * 72 + dim8] = kv;
        #pragma unroll
        for (int j = 0; j < 8; j++) {
            int d = dim8 + j;
            Vt[VSL(d, row8)] = vv[j];
        }
        __syncthreads();

        short8 kA0 = *(short8*)&Ks[col * 72 + quad * 8];
        short8 kA1 = *(short8*)&Ks[col * 72 + 32 + quad * 8];
        short8 kB0 = *(short8*)&Ks[(16 + col) * 72 + quad * 8];
        short8 kB1 = *(short8*)&Ks[(16 + col) * 72 + 32 + quad * 8];
        float4v sA = {0,0,0,0}, sB = {0,0,0,0};
        sA = __builtin_amdgcn_mfma_f32_16x16x32_bf16(qf0, kA0, sA, 0, 0, 0);
        sA = __builtin_amdgcn_mfma_f32_16x16x32_bf16(qf1, kA1, sA, 0, 0, 0);
        sB = __builtin_amdgcn_mfma_f32_16x16x32_bf16(qf0, kB0, sB, 0, 0, 0);
        sB = __builtin_amdgcn_mfma_f32_16x16x32_bf16(qf1, kB1, sB, 0, 0, 0);

        if (c < 18) {
            int nlo = -ch0;            // col >= nlo  (jA >= 0)
            int nhi = 1023 - ch0;      // col <= nhi  (jA < 1024)
            #pragma unroll
            for (int r = 0; r < 4; r++) {
                int qq = qq0 + 16 * w + quad * 4 + r;
                int u  = qq - ch0;
                int lo = max(u - 256, nlo);
                int hi = min(u + 256, nhi);
                bool vA = (col >= lo) && (col <= hi);
                bool vB = (col + 16 >= lo) && (col + 16 <= hi);
                float pa = vA ? exp2f(sA[r] * SCALE2) : 0.f;
                float pb = vB ? exp2f(sB[r] * SCALE2) : 0.f;
                lst[r] += pa + pb;
                Ps[(w * 16 + quad * 4 + r) * 40 + col]      = f2bf(pa);
                Ps[(w * 16 + quad * 4 + r) * 40 + col + 16] = f2bf(pb);
            }
        } else {
            #pragma unroll
            for (int r = 0; r < 4; r++) {
                int qq = qq0 + 16 * w + quad * 4 + r;
                int i = 2 * qq + p;
                int jA = gjs[col], jB = gjs[col + 16];
                int dA = jA - i, dB = jB - i;
                int aA = dA < 0 ? -dA : dA;
                int aB = dB < 0 ? -dB : dB;
                bool vA = (jA >= 0) && !((aA <= 512) && ((dA & 1) == 0));
                bool vB = (jB >= 0) && !((aB <= 512) && ((dB & 1) == 0));
                float pa = vA ? exp2f(sA[r] * SCALE2) : 0.f;
                float pb = vB ? exp2f(sB[r] * SCALE2) : 0.f;
                lst[r] += pa + pb;
                Ps[(w * 16 + quad * 4 + r) * 40 + col]      = f2bf(pa);
                Ps[(w * 16 + quad * 4 + r) * 40 + col + 16] = f2bf(pb);
            }
        }
        asm volatile("s_waitcnt lgkmcnt(0)" ::: "memory");

        short8 pf  = *(short8*)&Ps[(w * 16 + col) * 40 + quad * 8];
        short8 vf0 = *(short8*)&Vt[(col) * 40 + ((quad ^ ((col >> 3) & 3)) << 3)];
        short8 vf1 = *(short8*)&Vt[(16 + col) * 40 + ((quad ^ (((16 + col) >> 3) & 3)) << 3)];
        short8 vf2 = *(short8*)&Vt[(32 + col) * 40 + ((quad ^ (((32 + col) >> 3) & 3)) << 3)];
        short8 vf3 = *(short8*)&Vt[(48 + col) * 40 + ((quad ^ (((48 + col) >> 3) & 3)) << 3)];
        O0 = __builtin_amdgcn_mfma_f32_16x16x32_bf16(pf, vf0, O0, 0, 0, 0);
        O1 = __builtin_amdgcn_mfma_f32_16x16x32_bf16(pf, vf1, O1, 0, 0, 0);
        O2 = __builtin_amdgcn_mfma_f32_16x16x32_bf16(pf, vf2, O2, 0, 0, 0);
        O3 = __builtin_amdgcn_mfma_f32_16x16x32_bf16(pf, vf3, O3, 0, 0, 0);
    }

    #pragma unroll
    for (int r = 0; r < 4; r++) {
        float l = lst[r];
        #pragma unroll
        for (int mk = 1; mk < 16; mk <<= 1) l += __shfl_xor(l, mk);
        float inv = 1.0f / l;
        int q = 16 * w + quad * 4 + r;
        int i = 2 * (qq0 + q) + p;
        short* dst = ao + ((size_t)b * SS + i) * DMM + h * HDD;
        dst[col]      = f2bf(O0[r] * inv);
        dst[col + 16] = f2bf(O1[r] * inv);
        dst[col + 32] = f2bf(O2[r] * inv);
        dst[col + 48] = f2bf(O3[r] * inv);
    }
}

// ---------------- global rows: split-K MFMA partials (no-max softmax) ----------------
__global__ __launch_bounds__(256)
void global_part(const short* __restrict__ qh, const short* __restrict__ kh,
                 const short* __restrict__ vh, const int* __restrict__ glist,
                 const int* __restrict__ gcount,
                 float* __restrict__ pl, float* __restrict__ pO) {
    __shared__ short Qs[32 * 72];
    __shared__ short Ks[2][32 * 72];
    __shared__ short Vt[2][64 * 40];
    __shared__ short Ps[4 * 16 * 40];

    int t = threadIdx.x;
    int s = blockIdx.x, h = blockIdx.y, b = blockIdx.z;
    int nG = *gcount;

    const short* Qb = qh + ((size_t)(b * HH + h) * SS) * HDD;
    const short* Kb = kh + ((size_t)(b * HH + h) * SS) * HDD;
    const short* Vb = vh + ((size_t)(b * HH + h) * SS) * HDD;

    int row8 = t >> 3, dim8 = (t & 7) * 8;
    {
        int cq = row8 < nG ? row8 : 0;
        int src = glist[cq];
        short8 qv = *(const short8*)(Qb + (size_t)src * HDD + dim8);
        *(short8*)&Qs[row8 * 72 + dim8] = qv;
    }
    __syncthreads();

    int lane = t & 63, w = t >> 6;
    int quad = lane >> 4, col = lane & 15;
    int g = w >> 1, qt = w & 1;

    short8 qf0 = *(short8*)&Qs[(qt * 16 + col) * 72 + quad * 8];
    short8 qf1 = *(short8*)&Qs[(qt * 16 + col) * 72 + 32 + quad * 8];

    float4v O0 = {0,0,0,0}, O1 = {0,0,0,0}, O2 = {0,0,0,0}, O3 = {0,0,0,0};
    float lst[4] = {0.f, 0.f, 0.f, 0.f};

    int js0 = s * 256;
    for (int it = 0; it < 4; it++) {
        __syncthreads();
        int r64 = t >> 2, dimb = (t & 3) * 16;
        int j = js0 + it * 64 + r64;
        const short* kp = Kb + (size_t)j * HDD + dimb;
        const short* vp = Vb + (size_t)j * HDD + dimb;
        short8 k0 = *(const short8*)kp, k1 = *(const short8*)(kp + 8);
        short8 v0 = *(const short8*)vp, v1 = *(const short8*)(vp + 8);
        int half = r64 >> 5, r32 = r64 & 31;
        *(short8*)&Ks[half][r32 * 72 + dimb]     = k0;
        *(short8*)&Ks[half][r32 * 72 + dimb + 8] = k1;
        #pragma unroll
        for (int u = 0; u < 8; u++) {
            int d = dimb + u;
            Vt[half][VSL(d, r32)] = v0[u];
        }
        #pragma unroll
        for (int u = 0; u < 8; u++) {
            int d = dimb + 8 + u;
            Vt[half][VSL(d, r32)] = v1[u];
        }
        __syncthreads();

        short8 kA0 = *(short8*)&Ks[g][col * 72 + quad * 8];
        short8 kA1 = *(short8*)&Ks[g][col * 72 + 32 + quad * 8];
        short8 kB0 = *(short8*)&Ks[g][(16 + col) * 72 + quad * 8];
        short8 kB1 = *(short8*)&Ks[g][(16 + col) * 72 + 32 + quad * 8];
        float4v sA = {0,0,0,0}, sB = {0,0,0,0};
        sA = __builtin_amdgcn_mfma_f32_16x16x32_bf16(qf0, kA0, sA, 0, 0, 0);
        sA = __builtin_amdgcn_mfma_f32_16x16x32_bf16(qf1, kA1, sA, 0, 0, 0);
        sB = __builtin_amdgcn_mfma_f32_16x16x32_bf16(qf0, kB0, sB, 0, 0, 0);
        sB = __builtin_amdgcn_mfma_f32_16x16x32_bf16(qf1, kB1, sB, 0, 0, 0);

        #pragma unroll
        for (int r = 0; r < 4; r++) {
            float pa = exp2f(sA[r] * SCALE2);
            float pb = exp2f(sB[r] * SCALE2);
            lst[r] += pa + pb;
            Ps[(w * 16 + quad * 4 + r) * 40 + col]      = f2bf(pa);
            Ps[(w * 16 + quad * 4 + r) * 40 + col + 16] = f2bf(pb);
        }
        asm volatile("s_waitcnt lgkmcnt(0)" ::: "memory");

        short8 pf  = *(short8*)&Ps[(w * 16 + col) * 40 + quad * 8];
        short8 vf0 = *(short8*)&Vt[g][(col) * 40 + ((quad ^ ((col >> 3) & 3)) << 3)];
        short8 vf1 = *(short8*)&Vt[g][(16 + col) * 40 + ((quad ^ (((16 + col) >> 3) & 3)) << 3)];
        short8 vf2 = *(short8*)&Vt[g][(32 + col) * 40 + ((quad ^ (((32 + col) >> 3) & 3)) << 3)];
        short8 vf3 = *(short8*)&Vt[g][(48 + col) * 40 + ((quad ^ (((48 + col) >> 3) & 3)) << 3)];
        O0 = __builtin_amdgcn_mfma_f32_16x16x32_bf16(pf, vf0, O0, 0, 0, 0);
        O1 = __builtin_amdgcn_mfma_f32_16x16x32_bf16(pf, vf1, O1, 0, 0, 0);
        O2 = __builtin_amdgcn_mfma_f32_16x16x32_bf16(pf, vf2, O2, 0, 0, 0);
        O3 = __builtin_amdgcn_mfma_f32_16x16x32_bf16(pf, vf3, O3, 0, 0, 0);
    }

    int sp = s * 2 + g;
    size_t base = ((size_t)(b * HH + h) * 16 + sp) * 32;
    #pragma unroll
    for (int r = 0; r < 4; r++) {
        float l = lst[r];
        #pragma unroll
        for (int mk = 1; mk < 16; mk <<= 1) l += __shfl_xor(l, mk);
        int q = qt * 16 + quad * 4 + r;
        if (col == 0) pl[base + q] = l;
        float* Od = pO + (base + q) * 64;
        Od[col]      = O0[r];
        Od[col + 16] = O1[r];
        Od[col + 32] = O2[r];
        Od[col + 48] = O3[r];
    }
}

// ---------------- merge 16 partials per (b,h): plain sums ----------------
__global__ __launch_bounds__(256)
void global_merge(const float* __restrict__ pl, const float* __restrict__ pO,
                  const int* __restrict__ glist, const int* __restrict__ gcount,
                  short* __restrict__ ao) {
    int h = blockIdx.x, b = blockIdx.y;
    int t = threadIdx.x;
    int d = t & 63, qg = t >> 6;
    int nG = *gcount;
    size_t bh = ((size_t)(b * HH + h) * 16) * 32;

    for (int q = qg; q < nG; q += 4) {
        float L = 0.f, acc = 0.f;
        #pragma unroll
        for (int sp = 0; sp < 16; sp++) {
            L   += pl[bh + sp * 32 + q];
            acc += pO[(bh + sp * 32 + q) * 64 + d];
        }
        int i = glist[q];
        ao[((size_t)b * SS + i) * DMM + h * HDD + d] = f2bf(acc / L);
    }
}

extern "C" void kernel_launch(void* const* d_in, const int* in_sizes, int n_in,
                              void* d_out, int out_size, void* d_ws, size_t ws_size,
                              hipStream_t stream) {
    const float* q  = (const float*)d_in[0];
    const float* k  = (const float*)d_in[1];
    const float* v  = (const float*)d_in[2];
    const float* Wq = (const float*)d_in[3];
    const float* Wk = (const float*)d_in[4];
    const float* Wv = (const float*)d_in[5];
    const float* Wo = (const float*)d_in[6];
    const float* bq = (const float*)d_in[7];
    const float* bk = (const float*)d_in[8];
    const float* bv = (const float*)d_in[9];
    const float* bo = (const float*)d_in[10];
    const int* gidx = (const int*)d_in[11];
    float* out = (float*)d_out;

    // ws (64.03 MB): 32KB hdr | qh,kh,vh,ao bf16 8MB ea | wbf 8MB | abf 24MB (aliased by pl+pO)
    const size_t NE = (size_t)BB * SS * DMM;   // 4M
    const size_t WE = (size_t)DMM * DMM;       // 1M
    int*   g      = (int*)d_ws;
    int*   glist  = g + SS;
    int*   gcount = glist + SS;
    short* qh     = (short*)((char*)d_ws + 32768);
    short* kh     = qh + NE;
    short* vh     = kh + NE;
    short* ao     = vh + NE;
    short* wbf    = ao + NE;
    short* wo     = wbf + 3 * WE;
    short* abf    = wbf + 4 * WE;          // dead after QKV gemm
    float* pl     = (float*)abf;           // alias: written by global_part (later)
    float* pO     = pl + 16384;

    setup_globals<<<1, 256, 0, stream>>>(gidx, g, glist, gcount);

    dim3 gc(2048, 7);
    convert_all<<<gc, 256, 0, stream>>>(q, k, v, Wq, Wk, Wv, Wo, abf, wbf);

    dim3 gq(256, 3);   // batched QKV, 128x128 tiles: 768 blocks = 3/CU
    gemm128<1, 1><<<gq, 256, 0, stream>>>(abf, wbf, bq, bk, bv, qh, kh, vh);

    band_attn<<<1024, 256, 0, stream>>>(qh, kh, vh, glist, gcount, ao);

    dim3 gp(8, HH, BB);
    global_part<<<gp, 256, 0, stream>>>(qh, kh, vh, glist, gcount, pl, pO);

    dim3 gm(HH, BB);
    global_merge<<<gm, 256, 0, stream>>>(pl, pO, glist, gcount, ao);

    dim3 go(256, 1);   // Wo: 128x128 tiles, 256 blocks = 1/CU
    gemm128<0, 0><<<go, 256, 0, stream>>>(ao, wo, bo, bo, bo, out, out, out);
}

// Round 2
// 236.282 us; speedup vs baseline: 1.0185x; 1.0185x over previous
//
#include <hip/hip_runtime.h>
#include <hip/hip_bf16.h>
#include <math.h>

#define BB 2
#define SS 2048
#define DMM 1024
#define HH 16
#define HDD 64
#define NGLOB 32
#define MM 4096   // B*S
#define SCALE2 0.18033688f   // 0.125 * log2(e): exp(s/8) == exp2(s*SCALE2)

typedef __attribute__((ext_vector_type(8))) short short8;
typedef __attribute__((ext_vector_type(4))) float float4v;

__device__ __forceinline__ short f2bf(float f) {
    union { float f; unsigned u; } x; x.f = f;
    unsigned r = (x.u + 0x7fffu + ((x.u >> 16) & 1u)) >> 16;  // RNE
    return (short)r;
}

// async 16B global->LDS (m97 path). LDS dest = wave-uniform base + lane*16.
#define ASYNC16(gp, lp) __builtin_amdgcn_global_load_lds( \
    (__attribute__((address_space(1))) void*)(gp), \
    (__attribute__((address_space(3))) void*)(lp), 16, 0, 0)

// Vt slot swizzle: key-chunk XORed with dim-derived tag -> breaks the
// dim*stride==0 (mod 32 banks) collapse on transpose stores (16-way -> 4-way).
#define VSL(dim, key) ((dim) * 40 + (((((key) >> 3) ^ (((dim) >> 3) & 3)) << 3) | ((key) & 7)))

// ---------------- setup: parallel dedup'd global list (order irrelevant) ----------------
__global__ void setup_globals(const int* __restrict__ gidx, int* __restrict__ g,
                              int* __restrict__ glist, int* __restrict__ gcount) {
    int t = threadIdx.x;
    for (int i = t; i < SS; i += 256) g[i] = 0;
    if (t == 0) *gcount = 0;
    __syncthreads();
    if (t < NGLOB) {
        int j = gidx[t];
        if (j >= 0 && j < SS) g[j] = 1;
    }
    __syncthreads();
    for (int j = t; j < SS; j += 256) {
        if (g[j]) {
            int p = atomicAdd(gcount, 1);
            glist[p] = j;
        }
    }
}

// ---------------- convert inputs q,k,v (4M ea) + 4 weights (1M ea) fp32 -> bf16 ----------------
__global__ __launch_bounds__(256)
void convert_all(const float* __restrict__ q, const float* __restrict__ k,
                 const float* __restrict__ v,
                 const float* __restrict__ w0, const float* __restrict__ w1,
                 const float* __restrict__ w2, const float* __restrict__ w3,
                 short* __restrict__ abf, short* __restrict__ wbf) {
    int z = blockIdx.y;
    const float* src;
    short* dst;
    size_t n;
    if (z < 3) {
        src = (z == 0) ? q : (z == 1) ? k : v;
        dst = abf + (size_t)z * ((size_t)MM * DMM);
        n = (size_t)MM * DMM;
    } else {
        int y = z - 3;
        src = (y == 0) ? w0 : (y == 1) ? w1 : (y == 2) ? w2 : w3;
        dst = wbf + (size_t)y * ((size_t)DMM * DMM);
        n = (size_t)DMM * DMM;
    }
    size_t i = ((size_t)blockIdx.x * 256 + threadIdx.x) * 8;
    if (i >= n) return;
    float4 a = *(const float4*)(src + i);
    float4 b = *(const float4*)(src + i + 4);
    short8 s;
    s[0]=f2bf(a.x); s[1]=f2bf(a.y); s[2]=f2bf(a.z); s[3]=f2bf(a.w);
    s[4]=f2bf(b.x); s[5]=f2bf(b.y); s[6]=f2bf(b.z); s[7]=f2bf(b.w);
    *(short8*)(dst + i) = s;
}

// ---------------- MFMA GEMM, 128x128 tile, 3-deep pipelined (T3/T4: counted vmcnt) ----------------
// Triple-buffered LDS; tiles t and t+1 in flight at all times; wait vmcnt(4) (tile t
// landed, 4 newer loads outstanding), never vmcnt(0) in the main loop. Raw s_barrier.
// 3-buffer rotation safety: buffer staged at iter it was last ds_read at it-1, and those
// reads are drained (compiler lgkmcnt before MFMA) before any wave passes this iter's barrier.
template<int OBF, int HEADSPLIT>
__global__ __launch_bounds__(256)
void gemm128(const short* __restrict__ Abase, const short* __restrict__ Wbase,
             const float* __restrict__ b0, const float* __restrict__ b1,
             const float* __restrict__ b2,
             void* __restrict__ O0p, void* __restrict__ O1p, void* __restrict__ O2p) {
    __shared__ short As[3][128 * 32];   // 24 KB
    __shared__ short Ws[3][128 * 32];   // 24 KB

    int t = threadIdx.x;
    int z = blockIdx.y;
    const short* A    = Abase + (size_t)z * ((size_t)MM * DMM);
    const short* W    = Wbase + (size_t)z * ((size_t)DMM * DMM);
    const float* bias = (z == 0) ? b0 : (z == 1) ? b1 : b2;
    void* outp        = (z == 0) ? O0p : (z == 1) ? O1p : O2p;

    int bid = blockIdx.x;
    int xcd = bid & 7, loc = bid >> 3;     // XCD round-robin, 32 blocks/XCD
    int nblk = loc & 7, mloc = loc >> 3;   // per-XCD: 4 m-blocks x 8 n-blocks
    int m0 = (xcd * 4 + mloc) * 128;       // A-panel/XCD 1MB + B-panel 2MB fits 4MB L2
    int n0 = nblk * 128;

    int lane = t & 63, w = t >> 6;
    int quad = lane >> 4, col = lane & 15;
    int wr = (w & 1) * 64;    // wave's 64x64 quadrant
    int wc = (w >> 1) * 64;

    float4v acc[4][4];
    #pragma unroll
    for (int i = 0; i < 4; i++)
        #pragma unroll
        for (int j = 0; j < 4; j++) acc[i][j] = (float4v){0, 0, 0, 0};

    int rowA = t >> 2,  kcA = (t & 3) * 8;
    const short* Ap = A + (size_t)(m0 + rowA) * DMM + kcA;
    const short* Wp = W + (size_t)(n0 + rowA) * DMM + kcA;

    // 4 loads/thread/tile: two 64-row halves of A-panel and of W-panel
    #define STAGE(bf, tt) do { int kk = (tt) * 32; \
        ASYNC16(Ap + kk,                      &As[bf][t * 8]); \
        ASYNC16(Ap + 64 * (size_t)DMM + kk,   &As[bf][2048 + t * 8]); \
        ASYNC16(Wp + kk,                      &Ws[bf][t * 8]); \
        ASYNC16(Wp + 64 * (size_t)DMM + kk,   &Ws[bf][2048 + t * 8]); \
    } while (0)

    STAGE(0, 0);
    STAGE(1, 1);

    int cur = 0;
    for (int it = 0; it < 32; it++) {
        // tile it done (4 oldest); tiles it+1 (and it+2 after stage) stay in flight
        if (it < 31) asm volatile("s_waitcnt vmcnt(4)" ::: "memory");
        else         asm volatile("s_waitcnt vmcnt(0)" ::: "memory");
        __builtin_amdgcn_s_barrier();

        int sb = cur - 1; if (sb < 0) sb = 2;    // == (it+2)%3
        if (it + 2 < 32) STAGE(sb, it + 2);

        short8 aF[4], bF[4];
        #pragma unroll
        for (int i = 0; i < 4; i++)
            aF[i] = *(short8*)&As[cur][(wr + 16 * i + col) * 32 + quad * 8];
        #pragma unroll
        for (int j = 0; j < 4; j++)
            bF[j] = *(short8*)&Ws[cur][(wc + 16 * j + col) * 32 + quad * 8];

        #pragma unroll
        for (int i = 0; i < 4; i++)
            #pragma unroll
            for (int j = 0; j < 4; j++)
                acc[i][j] = __builtin_amdgcn_mfma_f32_16x16x32_bf16(aF[i], bF[j], acc[i][j], 0, 0, 0);

        cur++; if (cur == 3) cur = 0;
    }
    #undef STAGE

    #pragma unroll
    for (int i = 0; i < 4; i++) {
        #pragma unroll
        for (int j = 0; j < 4; j++) {
            int n = n0 + wc + 16 * j + col;
            float bn = bias[n];
            #pragma unroll
            for (int r = 0; r < 4; r++) {
                int m = m0 + wr + 16 * i + quad * 4 + r;
                float val = acc[i][j][r] + bn;
                size_t idx;
                if (HEADSPLIT) {
                    int b = m >> 11;
                    int s = m & 2047;
                    int h = n >> 6;
                    int hd = n & 63;
                    idx = (((size_t)b * HH + h) * SS + s) * HDD + hd;
                } else {
                    idx = (size_t)m * DMM + n;
                }
                if (OBF) ((short*)outp)[idx] = f2bf(val);
                else     ((float*)outp)[idx] = val;
            }
        }
    }
}

// ---------------- banded MFMA attention (XCD-local, swizzled Vt, interval mask) ----------------
// 1D grid 1024: all 16 q-tiles of a (b,h,parity) group land on one XCD (L2 reuse).
__global__ __launch_bounds__(256)
void band_attn(const short* __restrict__ qh, const short* __restrict__ kh,
               const short* __restrict__ vh, const int* __restrict__ glist,
               const int* __restrict__ gcount, short* __restrict__ ao) {
    __shared__ short Qs[64 * 72];
    __shared__ short Ks[32 * 72];
    __shared__ short Vt[64 * 40];
    __shared__ short Ps[4 * 16 * 40];
    __shared__ int   gjs[32];

    int t = threadIdx.x;
    int bid = blockIdx.x;
    int xcd = bid & 7, idx = bid >> 3;
    int gl  = idx >> 4;             // 0..7: group slot within XCD
    int qt  = idx & 15;             // q-tile
    int gid = xcd * 8 + gl;         // 0..63 -> (z,h)
    int z   = gid >> 4;
    int h   = gid & 15;
    int b = z >> 1, p = z & 1;
    int qq0 = qt * 64;
    int nG = *gcount;

    const short* Qb = qh + ((size_t)(b * HH + h) * SS) * HDD;
    const short* Kb = kh + ((size_t)(b * HH + h) * SS) * HDD;
    const short* Vb = vh + ((size_t)(b * HH + h) * SS) * HDD;

    int row8 = t >> 3;
    int dim8 = (t & 7) * 8;

    #pragma unroll
    for (int rr = 0; rr < 2; rr++) {
        int row = rr * 32 + row8;
        int i = 2 * (qq0 + row) + p;
        short8 qv = *(const short8*)(Qb + (size_t)i * HDD + dim8);
        *(short8*)&Qs[row * 72 + dim8] = qv;
    }
    if (t < 32) gjs[t] = (t < nG) ? glist[t] : -1000000;
    __syncthreads();

    int lane = t & 63, w = t >> 6;
    int quad = lane >> 4, col = lane & 15;

    short8 qf0 = *(short8*)&Qs[(16 * w + col) * 72 + quad * 8];
    short8 qf1 = *(short8*)&Qs[(16 * w + col) * 72 + 32 + quad * 8];

    float4v O0 = {0,0,0,0}, O1 = {0,0,0,0}, O2 = {0,0,0,0}, O3 = {0,0,0,0};
    float lst[4] = {0.f, 0.f, 0.f, 0.f};

    for (int c = 0; c < 19; c++) {
        __syncthreads();
        int ch0 = qq0 - 256 + c * 32;
        int srow;
        if (c < 18) srow = 2 * (ch0 + row8) + p;
        else        srow = (row8 < nG) ? gjs[row8] : 0;
        srow = srow < 0 ? 0 : (srow > SS - 1 ? SS - 1 : srow);
        short8 kv = *(const short8*)(Kb + (size_t)srow * HDD + dim8);
        short8 vv = *(const short8*)(Vb + (size_t)srow * HDD + dim8);
        *(short8*)&Ks[row8 * 72 + dim8] = kv;
        #pragma unroll
        for (int j = 0; j < 8; j++) {
            int d = dim8 + j;
            Vt[VSL(d, row8)] = vv[j];
        }
        __syncthreads();

        short8 kA0 = *(short8*)&Ks[col * 72 + quad * 8];
        short8 kA1 = *(short8*)&Ks[col * 72 + 32 + quad * 8];
        short8 kB0 = *(short8*)&Ks[(16 + col) * 72 + quad * 8];
        short8 kB1 = *(short8*)&Ks[(16 + col) * 72 + 32 + quad * 8];
        float4v sA = {0,0,0,0}, sB = {0,0,0,0};
        sA = __builtin_amdgcn_mfma_f32_16x16x32_bf16(qf0, kA0, sA, 0, 0, 0);
        sA = __builtin_amdgcn_mfma_f32_16x16x32_bf16(qf1, kA1, sA, 0, 0, 0);
        sB = __builtin_amdgcn_mfma_f32_16x16x32_bf16(qf0, kB0, sB, 0, 0, 0);
        sB = __builtin_amdgcn_mfma_f32_16x16x32_bf16(qf1, kB1, sB, 0, 0, 0);

        if (c < 18) {
            int nlo = -ch0;            // col >= nlo  (jA >= 0)
            int nhi = 1023 - ch0;      // col <= nhi  (jA < 1024)
            #pragma unroll
            for (int r = 0; r < 4; r++) {
                int qq = qq0 + 16 * w + quad * 4 + r;
                int u  = qq - ch0;
                int lo = max(u - 256, nlo);
                int hi = min(u + 256, nhi);
                bool vA = (col >= lo) && (col <= hi);
                bool vB = (col + 16 >= lo) && (col + 16 <= hi);
                float pa = vA ? exp2f(sA[r] * SCALE2) : 0.f;
                float pb = vB ? exp2f(sB[r] * SCALE2) : 0.f;
                lst[r] += pa + pb;
                Ps[(w * 16 + quad * 4 + r) * 40 + col]      = f2bf(pa);
                Ps[(w * 16 + quad * 4 + r) * 40 + col + 16] = f2bf(pb);
            }
        } else {
            #pragma unroll
            for (int r = 0; r < 4; r++) {
                int qq = qq0 + 16 * w + quad * 4 + r;
                int i = 2 * qq + p;
                int jA = gjs[col], jB = gjs[col + 16];
                int dA = jA - i, dB = jB - i;
                int aA = dA < 0 ? -dA : dA;
                int aB = dB < 0 ? -dB : dB;
                bool vA = (jA >= 0) && !((aA <= 512) && ((dA & 1) == 0));
                bool vB = (jB >= 0) && !((aB <= 512) && ((dB & 1) == 0));
                float pa = vA ? exp2f(sA[r] * SCALE2) : 0.f;
                float pb = vB ? exp2f(sB[r] * SCALE2) : 0.f;
                lst[r] += pa + pb;
                Ps[(w * 16 + quad * 4 + r) * 40 + col]      = f2bf(pa);
                Ps[(w * 16 + quad * 4 + r) * 40 + col + 16] = f2bf(pb);
            }
        }
        asm volatile("s_waitcnt lgkmcnt(0)" ::: "memory");

        short8 pf  = *(short8*)&Ps[(w * 16 + col) * 40 + quad * 8];
        short8 vf0 = *(short8*)&Vt[(col) * 40 + ((quad ^ ((col >> 3) & 3)) << 3)];
        short8 vf1 = *(short8*)&Vt[(16 + col) * 40 + ((quad ^ (((16 + col) >> 3) & 3)) << 3)];
        short8 vf2 = *(short8*)&Vt[(32 + col) * 40 + ((quad ^ (((32 + col) >> 3) & 3)) << 3)];
        short8 vf3 = *(short8*)&Vt[(48 + col) * 40 + ((quad ^ (((48 + col) >> 3) & 3)) << 3)];
        O0 = __builtin_amdgcn_mfma_f32_16x16x32_bf16(pf, vf0, O0, 0, 0, 0);
        O1 = __builtin_amdgcn_mfma_f32_16x16x32_bf16(pf, vf1, O1, 0, 0, 0);
        O2 = __builtin_amdgcn_mfma_f32_16x16x32_bf16(pf, vf2, O2, 0, 0, 0);
        O3 = __builtin_amdgcn_mfma_f32_16x16x32_bf16(pf, vf3, O3, 0, 0, 0);
    }

    #pragma unroll
    for (int r = 0; r < 4; r++) {
        float l = lst[r];
        #pragma unroll
        for (int mk = 1; mk < 16; mk <<= 1) l += __shfl_xor(l, mk);
        float inv = 1.0f / l;
        int q = 16 * w + quad * 4 + r;
        int i = 2 * (qq0 + q) + p;
        short* dst = ao + ((size_t)b * SS + i) * DMM + h * HDD;
        dst[col]      = f2bf(O0[r] * inv);
        dst[col + 16] = f2bf(O1[r] * inv);
        dst[col + 32] = f2bf(O2[r] * inv);
        dst[col + 48] = f2bf(O3[r] * inv);
    }
}

// ---------------- global rows: split-K MFMA partials (no-max softmax) ----------------
__global__ __launch_bounds__(256)
void global_part(const short* __restrict__ qh, const short* __restrict__ kh,
                 const short* __restrict__ vh, const int* __restrict__ glist,
                 const int* __restrict__ gcount,
                 float* __restrict__ pl, float* __restrict__ pO) {
    __shared__ short Qs[32 * 72];
    __shared__ short Ks[2][32 * 72];
    __shared__ short Vt[2][64 * 40];
    __shared__ short Ps[4 * 16 * 40];

    int t = threadIdx.x;
    int s = blockIdx.x, h = blockIdx.y, b = blockIdx.z;
    int nG = *gcount;

    const short* Qb = qh + ((size_t)(b * HH + h) * SS) * HDD;
    const short* Kb = kh + ((size_t)(b * HH + h) * SS) * HDD;
    const short* Vb = vh + ((size_t)(b * HH + h) * SS) * HDD;

    int row8 = t >> 3, dim8 = (t & 7) * 8;
    {
        int cq = row8 < nG ? row8 : 0;
        int src = glist[cq];
        short8 qv = *(const short8*)(Qb + (size_t)src * HDD + dim8);
        *(short8*)&Qs[row8 * 72 + dim8] = qv;
    }
    __syncthreads();

    int lane = t & 63, w = t >> 6;
    int quad = lane >> 4, col = lane & 15;
    int g = w >> 1, qt = w & 1;

    short8 qf0 = *(short8*)&Qs[(qt * 16 + col) * 72 + quad * 8];
    short8 qf1 = *(short8*)&Qs[(qt * 16 + col) * 72 + 32 + quad * 8];

    float4v O0 = {0,0,0,0}, O1 = {0,0,0,0}, O2 = {0,0,0,0}, O3 = {0,0,0,0};
    float lst[4] = {0.f, 0.f, 0.f, 0.f};

    int js0 = s * 256;
    for (int it = 0; it < 4; it++) {
        __syncthreads();
        int r64 = t >> 2, dimb = (t & 3) * 16;
        int j = js0 + it * 64 + r64;
        const short* kp = Kb + (size_t)j * HDD + dimb;
        const short* vp = Vb + (size_t)j * HDD + dimb;
        short8 k0 = *(const short8*)kp, k1 = *(const short8*)(kp + 8);
        short8 v0 = *(const short8*)vp, v1 = *(const short8*)(vp + 8);
        int half = r64 >> 5, r32 = r64 & 31;
        *(short8*)&Ks[half][r32 * 72 + dimb]     = k0;
        *(short8*)&Ks[half][r32 * 72 + dimb + 8] = k1;
        #pragma unroll
        for (int u = 0; u < 8; u++) {
            int d = dimb + u;
            Vt[half][VSL(d, r32)] = v0[u];
        }
        #pragma unroll
        for (int u = 0; u < 8; u++) {
            int d = dimb + 8 + u;
            Vt[half][VSL(d, r32)] = v1[u];
        }
        __syncthreads();

        short8 kA0 = *(short8*)&Ks[g][col * 72 + quad * 8];
        short8 kA1 = *(short8*)&Ks[g][col * 72 + 32 + quad * 8];
        short8 kB0 = *(short8*)&Ks[g][(16 + col) * 72 + quad * 8];
        short8 kB1 = *(short8*)&Ks[g][(16 + col) * 72 + 32 + quad * 8];
        float4v sA = {0,0,0,0}, sB = {0,0,0,0};
        sA = __builtin_amdgcn_mfma_f32_16x16x32_bf16(qf0, kA0, sA, 0, 0, 0);
        sA = __builtin_amdgcn_mfma_f32_16x16x32_bf16(qf1, kA1, sA, 0, 0, 0);
        sB = __builtin_amdgcn_mfma_f32_16x16x32_bf16(qf0, kB0, sB, 0, 0, 0);
        sB = __builtin_amdgcn_mfma_f32_16x16x32_bf16(qf1, kB1, sB, 0, 0, 0);

        #pragma unroll
        for (int r = 0; r < 4; r++) {
            float pa = exp2f(sA[r] * SCALE2);
            float pb = exp2f(sB[r] * SCALE2);
            lst[r] += pa + pb;
            Ps[(w * 16 + quad * 4 + r) * 40 + col]      = f2bf(pa);
            Ps[(w * 16 + quad * 4 + r) * 40 + col + 16] = f2bf(pb);
        }
        asm volatile("s_waitcnt lgkmcnt(0)" ::: "memory");

        short8 pf  = *(short8*)&Ps[(w * 16 + col) * 40 + quad * 8];
        short8 vf0 = *(short8*)&Vt[g][(col) * 40 + ((quad ^ ((col >> 3) & 3)) << 3)];
        short8 vf1 = *(short8*)&Vt[g][(16 + col) * 40 + ((quad ^ (((16 + col) >> 3) & 3)) << 3)];
        short8 vf2 = *(short8*)&Vt[g][(32 + col) * 40 + ((quad ^ (((32 + col) >> 3) & 3)) << 3)];
        short8 vf3 = *(short8*)&Vt[g][(48 + col) * 40 + ((quad ^ (((48 + col) >> 3) & 3)) << 3)];
        O0 = __builtin_amdgcn_mfma_f32_16x16x32_bf16(pf, vf0, O0, 0, 0, 0);
        O1 = __builtin_amdgcn_mfma_f32_16x16x32_bf16(pf, vf1, O1, 0, 0, 0);
        O2 = __builtin_amdgcn_mfma_f32_16x16x32_bf16(pf, vf2, O2, 0, 0, 0);
        O3 = __builtin_amdgcn_mfma_f32_16x16x32_bf16(pf, vf3, O3, 0, 0, 0);
    }

    int sp = s * 2 + g;
    size_t base = ((size_t)(b * HH + h) * 16 + sp) * 32;
    #pragma unroll
    for (int r = 0; r < 4; r++) {
        float l = lst[r];
        #pragma unroll
        for (int mk = 1; mk < 16; mk <<= 1) l += __shfl_xor(l, mk);
        int q = qt * 16 + quad * 4 + r;
        if (col == 0) pl[base + q] = l;
        float* Od = pO + (base + q) * 64;
        Od[col]      = O0[r];
        Od[col + 16] = O1[r];
        Od[col + 32] = O2[r];
        Od[col + 48] = O3[r];
    }
}

// ---------------- merge 16 partials per (b,h): plain sums ----------------
__global__ __launch_bounds__(256)
void global_merge(const float* __restrict__ pl, const float* __restrict__ pO,
                  const int* __restrict__ glist, const int* __restrict__ gcount,
                  short* __restrict__ ao) {
    int h = blockIdx.x, b = blockIdx.y;
    int t = threadIdx.x;
    int d = t & 63, qg = t >> 6;
    int nG = *gcount;
    size_t bh = ((size_t)(b * HH + h) * 16) * 32;

    for (int q = qg; q < nG; q += 4) {
        float L = 0.f, acc = 0.f;
        #pragma unroll
        for (int sp = 0; sp < 16; sp++) {
            L   += pl[bh + sp * 32 + q];
            acc += pO[(bh + sp * 32 + q) * 64 + d];
        }
        int i = glist[q];
        ao[((size_t)b * SS + i) * DMM + h * HDD + d] = f2bf(acc / L);
    }
}

extern "C" void kernel_launch(void* const* d_in, const int* in_sizes, int n_in,
                              void* d_out, int out_size, void* d_ws, size_t ws_size,
                              hipStream_t stream) {
    const float* q  = (const float*)d_in[0];
    const float* k  = (const float*)d_in[1];
    const float* v  = (const float*)d_in[2];
    const float* Wq = (const float*)d_in[3];
    const float* Wk = (const float*)d_in[4];
    const float* Wv = (const float*)d_in[5];
    const float* Wo = (const float*)d_in[6];
    const float* bq = (const float*)d_in[7];
    const float* bk = (const float*)d_in[8];
    const float* bv = (const float*)d_in[9];
    const float* bo = (const float*)d_in[10];
    const int* gidx = (const int*)d_in[11];
    float* out = (float*)d_out;

    // ws (64.03 MB): 32KB hdr | qh,kh,vh,ao bf16 8MB ea | wbf 8MB | abf 24MB (aliased by pl+pO)
    const size_t NE = (size_t)BB * SS * DMM;   // 4M
    const size_t WE = (size_t)DMM * DMM;       // 1M
    int*   g      = (int*)d_ws;
    int*   glist  = g + SS;
    int*   gcount = glist + SS;
    short* qh     = (short*)((char*)d_ws + 32768);
    short* kh     = qh + NE;
    short* vh     = kh + NE;
    short* ao     = vh + NE;
    short* wbf    = ao + NE;
    short* wo     = wbf + 3 * WE;
    short* abf    = wbf + 4 * WE;          // dead after QKV gemm
    float* pl     = (float*)abf;           // alias: written by global_part (later)
    float* pO     = pl + 16384;

    setup_globals<<<1, 256, 0, stream>>>(gidx, g, glist, gcount);

    dim3 gc(2048, 7);
    convert_all<<<gc, 256, 0, stream>>>(q, k, v, Wq, Wk, Wv, Wo, abf, wbf);

    dim3 gq(256, 3);   // batched QKV, 128x128 tiles: 768 blocks = 3/CU
    gemm128<1, 1><<<gq, 256, 0, stream>>>(abf, wbf, bq, bk, bv, qh, kh, vh);

    band_attn<<<1024, 256, 0, stream>>>(qh, kh, vh, glist, gcount, ao);

    dim3 gp(8, HH, BB);
    global_part<<<gp, 256, 0, stream>>>(qh, kh, vh, glist, gcount, pl, pO);

    dim3 gm(HH, BB);
    global_merge<<<gm, 256, 0, stream>>>(pl, pO, glist, gcount, ao);

    dim3 go(256, 1);   // Wo: 128x128 tiles, 256 blocks = 1/CU
    gemm128<0, 0><<<go, 256, 0, stream>>>(ao, wo, bo, bo, bo, out, out, out);
}

// Round 3
// 234.781 us; speedup vs baseline: 1.0250x; 1.0064x over previous
//
#include <hip/hip_runtime.h>
#include <hip/hip_bf16.h>
#include <math.h>

#define BB 2
#define SS 2048
#define DMM 1024
#define HH 16
#define HDD 64
#define NGLOB 32
#define MM 4096   // B*S
#define SCALE2 0.18033688f   // 0.125 * log2(e): exp(s/8) == exp2(s*SCALE2)

typedef __attribute__((ext_vector_type(8))) short short8;
typedef __attribute__((ext_vector_type(4))) float float4v;

__device__ __forceinline__ short f2bf(float f) {
    union { float f; unsigned u; } x; x.f = f;
    unsigned r = (x.u + 0x7fffu + ((x.u >> 16) & 1u)) >> 16;  // RNE
    return (short)r;
}

// async 16B global->LDS (m97 path). LDS dest = wave-uniform base + lane*16.
#define ASYNC16(gp, lp) __builtin_amdgcn_global_load_lds( \
    (__attribute__((address_space(1))) void*)(gp), \
    (__attribute__((address_space(3))) void*)(lp), 16, 0, 0)

// Vt slot swizzle: key-chunk XORed with dim-derived tag -> breaks the
// dim*stride==0 (mod 32 banks) collapse on transpose stores (16-way -> 4-way).
#define VSL(dim, key) ((dim) * 40 + (((((key) >> 3) ^ (((dim) >> 3) & 3)) << 3) | ((key) & 7)))

// ---------------- setup: parallel dedup'd global list (order irrelevant) ----------------
__global__ void setup_globals(const int* __restrict__ gidx, int* __restrict__ g,
                              int* __restrict__ glist, int* __restrict__ gcount) {
    int t = threadIdx.x;
    for (int i = t; i < SS; i += 256) g[i] = 0;
    if (t == 0) *gcount = 0;
    __syncthreads();
    if (t < NGLOB) {
        int j = gidx[t];
        if (j >= 0 && j < SS) g[j] = 1;
    }
    __syncthreads();
    for (int j = t; j < SS; j += 256) {
        if (g[j]) {
            int p = atomicAdd(gcount, 1);
            glist[p] = j;
        }
    }
}

// ---------------- convert inputs q,k,v (4M ea) + 4 weights (1M ea) fp32 -> bf16 ----------------
__global__ __launch_bounds__(256)
void convert_all(const float* __restrict__ q, const float* __restrict__ k,
                 const float* __restrict__ v,
                 const float* __restrict__ w0, const float* __restrict__ w1,
                 const float* __restrict__ w2, const float* __restrict__ w3,
                 short* __restrict__ abf, short* __restrict__ wbf) {
    int z = blockIdx.y;
    const float* src;
    short* dst;
    size_t n;
    if (z < 3) {
        src = (z == 0) ? q : (z == 1) ? k : v;
        dst = abf + (size_t)z * ((size_t)MM * DMM);
        n = (size_t)MM * DMM;
    } else {
        int y = z - 3;
        src = (y == 0) ? w0 : (y == 1) ? w1 : (y == 2) ? w2 : w3;
        dst = wbf + (size_t)y * ((size_t)DMM * DMM);
        n = (size_t)DMM * DMM;
    }
    size_t i = ((size_t)blockIdx.x * 256 + threadIdx.x) * 8;
    if (i >= n) return;
    float4 a = *(const float4*)(src + i);
    float4 b = *(const float4*)(src + i + 4);
    short8 s;
    s[0]=f2bf(a.x); s[1]=f2bf(a.y); s[2]=f2bf(a.z); s[3]=f2bf(a.w);
    s[4]=f2bf(b.x); s[5]=f2bf(b.y); s[6]=f2bf(b.z); s[7]=f2bf(b.w);
    *(short8*)(dst + i) = s;
}

// ---------------- MFMA GEMM, 128x128 tile, T3-minimum 2-phase (issue-early, drain0) ----
// 2-buffer 32 KB LDS -> 3+ blocks/CU (768-block QKV grid fully resident, single pass).
// Per iter: STAGE(next) issued FIRST; ds_read(cur); MFMA (setprio); vmcnt(0); s_barrier.
// The drain pays only residual load latency after a full compute phase (T3 recipe,
// m230/m248-verified). Buffer safety: STAGE(buf^1) targets the buffer last read at
// it-1, whose readers passed the it-1 end-barrier before this STAGE issues.
template<int OBF, int HEADSPLIT>
__global__ __launch_bounds__(256)
void gemm128(const short* __restrict__ Abase, const short* __restrict__ Wbase,
             const float* __restrict__ b0, const float* __restrict__ b1,
             const float* __restrict__ b2,
             void* __restrict__ O0p, void* __restrict__ O1p, void* __restrict__ O2p) {
    __shared__ short As[2][128 * 32];   // 16 KB
    __shared__ short Ws[2][128 * 32];   // 16 KB

    int t = threadIdx.x;
    int z = blockIdx.y;
    const short* A    = Abase + (size_t)z * ((size_t)MM * DMM);
    const short* W    = Wbase + (size_t)z * ((size_t)DMM * DMM);
    const float* bias = (z == 0) ? b0 : (z == 1) ? b1 : b2;
    void* outp        = (z == 0) ? O0p : (z == 1) ? O1p : O2p;

    int bid = blockIdx.x;
    int xcd = bid & 7, loc = bid >> 3;     // XCD round-robin, 32 blocks/XCD
    int nblk = loc & 7, mloc = loc >> 3;   // per-XCD: 4 m-blocks x 8 n-blocks
    int m0 = (xcd * 4 + mloc) * 128;       // A-panel/XCD 1MB + B-panel 2MB fits 4MB L2
    int n0 = nblk * 128;

    int lane = t & 63, w = t >> 6;
    int quad = lane >> 4, col = lane & 15;
    int wr = (w & 1) * 64;    // wave's 64x64 quadrant
    int wc = (w >> 1) * 64;

    float4v acc[4][4];
    #pragma unroll
    for (int i = 0; i < 4; i++)
        #pragma unroll
        for (int j = 0; j < 4; j++) acc[i][j] = (float4v){0, 0, 0, 0};

    int rowA = t >> 2,  kcA = (t & 3) * 8;
    const short* Ap = A + (size_t)(m0 + rowA) * DMM + kcA;
    const short* Wp = W + (size_t)(n0 + rowA) * DMM + kcA;

    // 4 loads/thread/tile: two 64-row halves of A-panel and of W-panel
    #define STAGE(bf, tt) do { int kk = (tt) * 32; \
        ASYNC16(Ap + kk,                      &As[bf][t * 8]); \
        ASYNC16(Ap + 64 * (size_t)DMM + kk,   &As[bf][2048 + t * 8]); \
        ASYNC16(Wp + kk,                      &Ws[bf][t * 8]); \
        ASYNC16(Wp + 64 * (size_t)DMM + kk,   &Ws[bf][2048 + t * 8]); \
    } while (0)

    STAGE(0, 0);
    asm volatile("s_waitcnt vmcnt(0)" ::: "memory");
    __builtin_amdgcn_s_barrier();

    for (int it = 0; it < 32; it++) {
        int cur = it & 1;
        if (it + 1 < 32) STAGE(cur ^ 1, it + 1);   // issue next tile's loads FIRST

        short8 aF[4], bF[4];
        #pragma unroll
        for (int i = 0; i < 4; i++)
            aF[i] = *(short8*)&As[cur][(wr + 16 * i + col) * 32 + quad * 8];
        #pragma unroll
        for (int j = 0; j < 4; j++)
            bF[j] = *(short8*)&Ws[cur][(wc + 16 * j + col) * 32 + quad * 8];

        __builtin_amdgcn_s_setprio(1);
        #pragma unroll
        for (int i = 0; i < 4; i++)
            #pragma unroll
            for (int j = 0; j < 4; j++)
                acc[i][j] = __builtin_amdgcn_mfma_f32_16x16x32_bf16(aF[i], bF[j], acc[i][j], 0, 0, 0);
        __builtin_amdgcn_s_setprio(0);

        // next tile fully landed (issued a whole compute phase ago), then release buffers
        asm volatile("s_waitcnt vmcnt(0)" ::: "memory");
        __builtin_amdgcn_s_barrier();
    }
    #undef STAGE

    #pragma unroll
    for (int i = 0; i < 4; i++) {
        #pragma unroll
        for (int j = 0; j < 4; j++) {
            int n = n0 + wc + 16 * j + col;
            float bn = bias[n];
            #pragma unroll
            for (int r = 0; r < 4; r++) {
                int m = m0 + wr + 16 * i + quad * 4 + r;
                float val = acc[i][j][r] + bn;
                size_t idx;
                if (HEADSPLIT) {
                    int b = m >> 11;
                    int s = m & 2047;
                    int h = n >> 6;
                    int hd = n & 63;
                    idx = (((size_t)b * HH + h) * SS + s) * HDD + hd;
                } else {
                    idx = (size_t)m * DMM + n;
                }
                if (OBF) ((short*)outp)[idx] = f2bf(val);
                else     ((float*)outp)[idx] = val;
            }
        }
    }
}

// ---------------- banded MFMA attention (XCD-local, swizzled Vt, interval mask) ----------------
// 1D grid 1024: all 16 q-tiles of a (b,h,parity) group land on one XCD (L2 reuse).
// K/V loads for chunk c+1 are issued in registers while chunk c computes (T14
// issue-early/write-late): load latency hides under QK^T+softmax+PV instead of
// sitting serially on the 19-chunk critical path.
__global__ __launch_bounds__(256)
void band_attn(const short* __restrict__ qh, const short* __restrict__ kh,
               const short* __restrict__ vh, const int* __restrict__ glist,
               const int* __restrict__ gcount, short* __restrict__ ao) {
    __shared__ short Qs[64 * 72];
    __shared__ short Ks[32 * 72];
    __shared__ short Vt[64 * 40];
    __shared__ short Ps[4 * 16 * 40];
    __shared__ int   gjs[32];

    int t = threadIdx.x;
    int bid = blockIdx.x;
    int xcd = bid & 7, idx = bid >> 3;
    int gl  = idx >> 4;             // 0..7: group slot within XCD
    int qt  = idx & 15;             // q-tile
    int gid = xcd * 8 + gl;         // 0..63 -> (z,h)
    int z   = gid >> 4;
    int h   = gid & 15;
    int b = z >> 1, p = z & 1;
    int qq0 = qt * 64;
    int nG = *gcount;

    const short* Qb = qh + ((size_t)(b * HH + h) * SS) * HDD;
    const short* Kb = kh + ((size_t)(b * HH + h) * SS) * HDD;
    const short* Vb = vh + ((size_t)(b * HH + h) * SS) * HDD;

    int row8 = t >> 3;
    int dim8 = (t & 7) * 8;

    #pragma unroll
    for (int rr = 0; rr < 2; rr++) {
        int row = rr * 32 + row8;
        int i = 2 * (qq0 + row) + p;
        short8 qv = *(const short8*)(Qb + (size_t)i * HDD + dim8);
        *(short8*)&Qs[row * 72 + dim8] = qv;
    }
    if (t < 32) gjs[t] = (t < nG) ? glist[t] : -1000000;
    __syncthreads();

    int lane = t & 63, w = t >> 6;
    int quad = lane >> 4, col = lane & 15;

    short8 qf0 = *(short8*)&Qs[(16 * w + col) * 72 + quad * 8];
    short8 qf1 = *(short8*)&Qs[(16 * w + col) * 72 + 32 + quad * 8];

    float4v O0 = {0,0,0,0}, O1 = {0,0,0,0}, O2 = {0,0,0,0}, O3 = {0,0,0,0};
    float lst[4] = {0.f, 0.f, 0.f, 0.f};

    // prologue: prefetch chunk 0's K/V rows into registers
    short8 kvP, vvP, kvN, vvN;
    {
        int srow = 2 * (qq0 - 256 + row8) + p;
        srow = srow < 0 ? 0 : (srow > SS - 1 ? SS - 1 : srow);
        kvP = *(const short8*)(Kb + (size_t)srow * HDD + dim8);
        vvP = *(const short8*)(Vb + (size_t)srow * HDD + dim8);
    }

    for (int c = 0; c < 19; c++) {
        __syncthreads();
        // write-late: store prefetched chunk c to LDS
        *(short8*)&Ks[row8 * 72 + dim8] = kvP;
        #pragma unroll
        for (int j = 0; j < 8; j++) {
            int d = dim8 + j;
            Vt[VSL(d, row8)] = vvP[j];
        }
        // issue-early: prefetch chunk c+1 (consumed after next barrier)
        if (c < 18) {
            int cn = c + 1;
            int ch0n = qq0 - 256 + cn * 32;
            int srow;
            if (cn < 18) srow = 2 * (ch0n + row8) + p;
            else         srow = (row8 < nG) ? gjs[row8] : 0;
            srow = srow < 0 ? 0 : (srow > SS - 1 ? SS - 1 : srow);
            kvN = *(const short8*)(Kb + (size_t)srow * HDD + dim8);
            vvN = *(const short8*)(Vb + (size_t)srow * HDD + dim8);
        }
        __syncthreads();

        int ch0 = qq0 - 256 + c * 32;

        short8 kA0 = *(short8*)&Ks[col * 72 + quad * 8];
        short8 kA1 = *(short8*)&Ks[col * 72 + 32 + quad * 8];
        short8 kB0 = *(short8*)&Ks[(16 + col) * 72 + quad * 8];
        short8 kB1 = *(short8*)&Ks[(16 + col) * 72 + 32 + quad * 8];
        float4v sA = {0,0,0,0}, sB = {0,0,0,0};
        sA = __builtin_amdgcn_mfma_f32_16x16x32_bf16(qf0, kA0, sA, 0, 0, 0);
        sA = __builtin_amdgcn_mfma_f32_16x16x32_bf16(qf1, kA1, sA, 0, 0, 0);
        sB = __builtin_amdgcn_mfma_f32_16x16x32_bf16(qf0, kB0, sB, 0, 0, 0);
        sB = __builtin_amdgcn_mfma_f32_16x16x32_bf16(qf1, kB1, sB, 0, 0, 0);

        if (c < 18) {
            int nlo = -ch0;            // col >= nlo  (jA >= 0)
            int nhi = 1023 - ch0;      // col <= nhi  (jA < 1024)
            #pragma unroll
            for (int r = 0; r < 4; r++) {
                int qq = qq0 + 16 * w + quad * 4 + r;
                int u  = qq - ch0;
                int lo = max(u - 256, nlo);
                int hi = min(u + 256, nhi);
                bool vA = (col >= lo) && (col <= hi);
                bool vB = (col + 16 >= lo) && (col + 16 <= hi);
                float pa = vA ? exp2f(sA[r] * SCALE2) : 0.f;
                float pb = vB ? exp2f(sB[r] * SCALE2) : 0.f;
                lst[r] += pa + pb;
                Ps[(w * 16 + quad * 4 + r) * 40 + col]      = f2bf(pa);
                Ps[(w * 16 + quad * 4 + r) * 40 + col + 16] = f2bf(pb);
            }
        } else {
            #pragma unroll
            for (int r = 0; r < 4; r++) {
                int qq = qq0 + 16 * w + quad * 4 + r;
                int i = 2 * qq + p;
                int jA = gjs[col], jB = gjs[col + 16];
                int dA = jA - i, dB = jB - i;
                int aA = dA < 0 ? -dA : dA;
                int aB = dB < 0 ? -dB : dB;
                bool vA = (jA >= 0) && !((aA <= 512) && ((dA & 1) == 0));
                bool vB = (jB >= 0) && !((aB <= 512) && ((dB & 1) == 0));
                float pa = vA ? exp2f(sA[r] * SCALE2) : 0.f;
                float pb = vB ? exp2f(sB[r] * SCALE2) : 0.f;
                lst[r] += pa + pb;
                Ps[(w * 16 + quad * 4 + r) * 40 + col]      = f2bf(pa);
                Ps[(w * 16 + quad * 4 + r) * 40 + col + 16] = f2bf(pb);
            }
        }
        asm volatile("s_waitcnt lgkmcnt(0)" ::: "memory");

        short8 pf  = *(short8*)&Ps[(w * 16 + col) * 40 + quad * 8];
        short8 vf0 = *(short8*)&Vt[(col) * 40 + ((quad ^ ((col >> 3) & 3)) << 3)];
        short8 vf1 = *(short8*)&Vt[(16 + col) * 40 + ((quad ^ (((16 + col) >> 3) & 3)) << 3)];
        short8 vf2 = *(short8*)&Vt[(32 + col) * 40 + ((quad ^ (((32 + col) >> 3) & 3)) << 3)];
        short8 vf3 = *(short8*)&Vt[(48 + col) * 40 + ((quad ^ (((48 + col) >> 3) & 3)) << 3)];
        O0 = __builtin_amdgcn_mfma_f32_16x16x32_bf16(pf, vf0, O0, 0, 0, 0);
        O1 = __builtin_amdgcn_mfma_f32_16x16x32_bf16(pf, vf1, O1, 0, 0, 0);
        O2 = __builtin_amdgcn_mfma_f32_16x16x32_bf16(pf, vf2, O2, 0, 0, 0);
        O3 = __builtin_amdgcn_mfma_f32_16x16x32_bf16(pf, vf3, O3, 0, 0, 0);

        kvP = kvN; vvP = vvN;
    }

    #pragma unroll
    for (int r = 0; r < 4; r++) {
        float l = lst[r];
        #pragma unroll
        for (int mk = 1; mk < 16; mk <<= 1) l += __shfl_xor(l, mk);
        float inv = 1.0f / l;
        int q = 16 * w + quad * 4 + r;
        int i = 2 * (qq0 + q) + p;
        short* dst = ao + ((size_t)b * SS + i) * DMM + h * HDD;
        dst[col]      = f2bf(O0[r] * inv);
        dst[col + 16] = f2bf(O1[r] * inv);
        dst[col + 32] = f2bf(O2[r] * inv);
        dst[col + 48] = f2bf(O3[r] * inv);
    }
}

// ---------------- global rows: split-K MFMA partials (no-max softmax) ----------------
__global__ __launch_bounds__(256)
void global_part(const short* __restrict__ qh, const short* __restrict__ kh,
                 const short* __restrict__ vh, const int* __restrict__ glist,
                 const int* __restrict__ gcount,
                 float* __restrict__ pl, float* __restrict__ pO) {
    __shared__ short Qs[32 * 72];
    __shared__ short Ks[2][32 * 72];
    __shared__ short Vt[2][64 * 40];
    __shared__ short Ps[4 * 16 * 40];

    int t = threadIdx.x;
    int s = blockIdx.x, h = blockIdx.y, b = blockIdx.z;
    int nG = *gcount;

    const short* Qb = qh + ((size_t)(b * HH + h) * SS) * HDD;
    const short* Kb = kh + ((size_t)(b * HH + h) * SS) * HDD;
    const short* Vb = vh + ((size_t)(b * HH + h) * SS) * HDD;

    int row8 = t >> 3, dim8 = (t & 7) * 8;
    {
        int cq = row8 < nG ? row8 : 0;
        int src = glist[cq];
        short8 qv = *(const short8*)(Qb + (size_t)src * HDD + dim8);
        *(short8*)&Qs[row8 * 72 + dim8] = qv;
    }
    __syncthreads();

    int lane = t & 63, w = t >> 6;
    int quad = lane >> 4, col = lane & 15;
    int g = w >> 1, qt = w & 1;

    short8 qf0 = *(short8*)&Qs[(qt * 16 + col) * 72 + quad * 8];
    short8 qf1 = *(short8*)&Qs[(qt * 16 + col) * 72 + 32 + quad * 8];

    float4v O0 = {0,0,0,0}, O1 = {0,0,0,0}, O2 = {0,0,0,0}, O3 = {0,0,0,0};
    float lst[4] = {0.f, 0.f, 0.f, 0.f};

    int js0 = s * 256;
    for (int it = 0; it < 4; it++) {
        __syncthreads();
        int r64 = t >> 2, dimb = (t & 3) * 16;
        int j = js0 + it * 64 + r64;
        const short* kp = Kb + (size_t)j * HDD + dimb;
        const short* vp = Vb + (size_t)j * HDD + dimb;
        short8 k0 = *(const short8*)kp, k1 = *(const short8*)(kp + 8);
        short8 v0 = *(const short8*)vp, v1 = *(const short8*)(vp + 8);
        int half = r64 >> 5, r32 = r64 & 31;
        *(short8*)&Ks[half][r32 * 72 + dimb]     = k0;
        *(short8*)&Ks[half][r32 * 72 + dimb + 8] = k1;
        #pragma unroll
        for (int u = 0; u < 8; u++) {
            int d = dimb + u;
            Vt[half][VSL(d, r32)] = v0[u];
        }
        #pragma unroll
        for (int u = 0; u < 8; u++) {
            int d = dimb + 8 + u;
            Vt[half][VSL(d, r32)] = v1[u];
        }
        __syncthreads();

        short8 kA0 = *(short8*)&Ks[g][col * 72 + quad * 8];
        short8 kA1 = *(short8*)&Ks[g][col * 72 + 32 + quad * 8];
        short8 kB0 = *(short8*)&Ks[g][(16 + col) * 72 + quad * 8];
        short8 kB1 = *(short8*)&Ks[g][(16 + col) * 72 + 32 + quad * 8];
        float4v sA = {0,0,0,0}, sB = {0,0,0,0};
        sA = __builtin_amdgcn_mfma_f32_16x16x32_bf16(qf0, kA0, sA, 0, 0, 0);
        sA = __builtin_amdgcn_mfma_f32_16x16x32_bf16(qf1, kA1, sA, 0, 0, 0);
        sB = __builtin_amdgcn_mfma_f32_16x16x32_bf16(qf0, kB0, sB, 0, 0, 0);
        sB = __builtin_amdgcn_mfma_f32_16x16x32_bf16(qf1, kB1, sB, 0, 0, 0);

        #pragma unroll
        for (int r = 0; r < 4; r++) {
            float pa = exp2f(sA[r] * SCALE2);
            float pb = exp2f(sB[r] * SCALE2);
            lst[r] += pa + pb;
            Ps[(w * 16 + quad * 4 + r) * 40 + col]      = f2bf(pa);
            Ps[(w * 16 + quad * 4 + r) * 40 + col + 16] = f2bf(pb);
        }
        asm volatile("s_waitcnt lgkmcnt(0)" ::: "memory");

        short8 pf  = *(short8*)&Ps[(w * 16 + col) * 40 + quad * 8];
        short8 vf0 = *(short8*)&Vt[g][(col) * 40 + ((quad ^ ((col >> 3) & 3)) << 3)];
        short8 vf1 = *(short8*)&Vt[g][(16 + col) * 40 + ((quad ^ (((16 + col) >> 3) & 3)) << 3)];
        short8 vf2 = *(short8*)&Vt[g][(32 + col) * 40 + ((quad ^ (((32 + col) >> 3) & 3)) << 3)];
        short8 vf3 = *(short8*)&Vt[g][(48 + col) * 40 + ((quad ^ (((48 + col) >> 3) & 3)) << 3)];
        O0 = __builtin_amdgcn_mfma_f32_16x16x32_bf16(pf, vf0, O0, 0, 0, 0);
        O1 = __builtin_amdgcn_mfma_f32_16x16x32_bf16(pf, vf1, O1, 0, 0, 0);
        O2 = __builtin_amdgcn_mfma_f32_16x16x32_bf16(pf, vf2, O2, 0, 0, 0);
        O3 = __builtin_amdgcn_mfma_f32_16x16x32_bf16(pf, vf3, O3, 0, 0, 0);
    }

    int sp = s * 2 + g;
    size_t base = ((size_t)(b * HH + h) * 16 + sp) * 32;
    #pragma unroll
    for (int r = 0; r < 4; r++) {
        float l = lst[r];
        #pragma unroll
        for (int mk = 1; mk < 16; mk <<= 1) l += __shfl_xor(l, mk);
        int q = qt * 16 + quad * 4 + r;
        if (col == 0) pl[base + q] = l;
        float* Od = pO + (base + q) * 64;
        Od[col]      = O0[r];
        Od[col + 16] = O1[r];
        Od[col + 32] = O2[r];
        Od[col + 48] = O3[r];
    }
}

// ---------------- merge 16 partials per (b,h): plain sums ----------------
__global__ __launch_bounds__(256)
void global_merge(const float* __restrict__ pl, const float* __restrict__ pO,
                  const int* __restrict__ glist, const int* __restrict__ gcount,
                  short* __restrict__ ao) {
    int h = blockIdx.x, b = blockIdx.y;
    int t = threadIdx.x;
    int d = t & 63, qg = t >> 6;
    int nG = *gcount;
    size_t bh = ((size_t)(b * HH + h) * 16) * 32;

    for (int q = qg; q < nG; q += 4) {
        float L = 0.f, acc = 0.f;
        #pragma unroll
        for (int sp = 0; sp < 16; sp++) {
            L   += pl[bh + sp * 32 + q];
            acc += pO[(bh + sp * 32 + q) * 64 + d];
        }
        int i = glist[q];
        ao[((size_t)b * SS + i) * DMM + h * HDD + d] = f2bf(acc / L);
    }
}

extern "C" void kernel_launch(void* const* d_in, const int* in_sizes, int n_in,
                              void* d_out, int out_size, void* d_ws, size_t ws_size,
                              hipStream_t stream) {
    const float* q  = (const float*)d_in[0];
    const float* k  = (const float*)d_in[1];
    const float* v  = (const float*)d_in[2];
    const float* Wq = (const float*)d_in[3];
    const float* Wk = (const float*)d_in[4];
    const float* Wv = (const float*)d_in[5];
    const float* Wo = (const float*)d_in[6];
    const float* bq = (const float*)d_in[7];
    const float* bk = (const float*)d_in[8];
    const float* bv = (const float*)d_in[9];
    const float* bo = (const float*)d_in[10];
    const int* gidx = (const int*)d_in[11];
    float* out = (float*)d_out;

    // ws (64.03 MB): 32KB hdr | qh,kh,vh,ao bf16 8MB ea | wbf 8MB | abf 24MB (aliased by pl+pO)
    const size_t NE = (size_t)BB * SS * DMM;   // 4M
    const size_t WE = (size_t)DMM * DMM;       // 1M
    int*   g      = (int*)d_ws;
    int*   glist  = g + SS;
    int*   gcount = glist + SS;
    short* qh     = (short*)((char*)d_ws + 32768);
    short* kh     = qh + NE;
    short* vh     = kh + NE;
    short* ao     = vh + NE;
    short* wbf    = ao + NE;
    short* wo     = wbf + 3 * WE;
    short* abf    = wbf + 4 * WE;          // dead after QKV gemm
    float* pl     = (float*)abf;           // alias: written by global_part (later)
    float* pO     = pl + 16384;

    setup_globals<<<1, 256, 0, stream>>>(gidx, g, glist, gcount);

    dim3 gc(2048, 7);
    convert_all<<<gc, 256, 0, stream>>>(q, k, v, Wq, Wk, Wv, Wo, abf, wbf);

    dim3 gq(256, 3);   // batched QKV, 128x128 tiles: 768 blocks = 3/CU, single pass
    gemm128<1, 1><<<gq, 256, 0, stream>>>(abf, wbf, bq, bk, bv, qh, kh, vh);

    band_attn<<<1024, 256, 0, stream>>>(qh, kh, vh, glist, gcount, ao);

    dim3 gp(8, HH, BB);
    global_part<<<gp, 256, 0, stream>>>(qh, kh, vh, glist, gcount, pl, pO);

    dim3 gm(HH, BB);
    global_merge<<<gm, 256, 0, stream>>>(pl, pO, glist, gcount, ao);

    dim3 go(256, 1);   // Wo: 128x128 tiles, 256 blocks = 1/CU
    gemm128<0, 0><<<go, 256, 0, stream>>>(ao, wo, bo, bo, bo, out, out, out);
}

// Round 4
// 232.298 us; speedup vs baseline: 1.0360x; 1.0107x over previous
//
#include <hip/hip_runtime.h>
#include <hip/hip_bf16.h>
#include <math.h>

#define BB 2
#define SS 2048
#define DMM 1024
#define HH 16
#define HDD 64
#define NGLOB 32
#define MM 4096   // B*S
#define SCALE2 0.18033688f   // 0.125 * log2(e): exp(s/8) == exp2(s*SCALE2)

typedef __attribute__((ext_vector_type(8))) short short8;
typedef __attribute__((ext_vector_type(4))) float float4v;

__device__ __forceinline__ short f2bf(float f) {
    union { float f; unsigned u; } x; x.f = f;
    unsigned r = (x.u + 0x7fffu + ((x.u >> 16) & 1u)) >> 16;  // RNE
    return (short)r;
}

// async 16B global->LDS (m97 path). LDS dest = wave-uniform base + lane*16.
#define ASYNC16(gp, lp) __builtin_amdgcn_global_load_lds( \
    (__attribute__((address_space(1))) void*)(gp), \
    (__attribute__((address_space(3))) void*)(lp), 16, 0, 0)

// Vt slot swizzle: key-chunk XORed with dim-derived tag -> breaks the
// dim*stride==0 (mod 32 banks) collapse on transpose stores (16-way -> 4-way).
#define VSL(dim, key) ((dim) * 40 + (((((key) >> 3) ^ (((dim) >> 3) & 3)) << 3) | ((key) & 7)))

// ---------------- setup: parallel dedup'd global list (order irrelevant) ----------------
__global__ void setup_globals(const int* __restrict__ gidx, int* __restrict__ g,
                              int* __restrict__ glist, int* __restrict__ gcount) {
    int t = threadIdx.x;
    for (int i = t; i < SS; i += 256) g[i] = 0;
    if (t == 0) *gcount = 0;
    __syncthreads();
    if (t < NGLOB) {
        int j = gidx[t];
        if (j >= 0 && j < SS) g[j] = 1;
    }
    __syncthreads();
    for (int j = t; j < SS; j += 256) {
        if (g[j]) {
            int p = atomicAdd(gcount, 1);
            glist[p] = j;
        }
    }
}

// ---------------- convert inputs q,k,v (4M ea) + 4 weights (1M ea) fp32 -> bf16 ----------------
__global__ __launch_bounds__(256)
void convert_all(const float* __restrict__ q, const float* __restrict__ k,
                 const float* __restrict__ v,
                 const float* __restrict__ w0, const float* __restrict__ w1,
                 const float* __restrict__ w2, const float* __restrict__ w3,
                 short* __restrict__ abf, short* __restrict__ wbf) {
    int z = blockIdx.y;
    const float* src;
    short* dst;
    size_t n;
    if (z < 3) {
        src = (z == 0) ? q : (z == 1) ? k : v;
        dst = abf + (size_t)z * ((size_t)MM * DMM);
        n = (size_t)MM * DMM;
    } else {
        int y = z - 3;
        src = (y == 0) ? w0 : (y == 1) ? w1 : (y == 2) ? w2 : w3;
        dst = wbf + (size_t)y * ((size_t)DMM * DMM);
        n = (size_t)DMM * DMM;
    }
    size_t i = ((size_t)blockIdx.x * 256 + threadIdx.x) * 8;
    if (i >= n) return;
    float4 a = *(const float4*)(src + i);
    float4 b = *(const float4*)(src + i + 4);
    short8 s;
    s[0]=f2bf(a.x); s[1]=f2bf(a.y); s[2]=f2bf(a.z); s[3]=f2bf(a.w);
    s[4]=f2bf(b.x); s[5]=f2bf(b.y); s[6]=f2bf(b.z); s[7]=f2bf(b.w);
    *(short8*)(dst + i) = s;
}

// ---------------- 256x256/BK=64 MFMA GEMM: T2 swizzle + T3/T4 counted vmcnt + T5 ----------------
// 512 threads = 8 waves (2M x 4N), wave tile 128x64, acc[8][4]. LDS 128 KB (2 dbuf).
// Per iter: burst-stage next K-tile (8 loads) -> s_waitcnt vmcnt(8) (current tile's 8
// oldest landed; next 8 stay in flight across the barrier; NEVER vmcnt(0) mid-loop) ->
// 4 MFMA phases with raw barriers + setprio. LDS bank-conflict-free via XOR involution:
// source column pre-swizzled ((t&7)^(row&7))*16B, ds_read applies the same XOR.
// WAR: end-of-iter barrier precedes next iter's stage into the buffer read this iter.
template<int OBF, int HEADSPLIT>
__global__ __launch_bounds__(512, 2)
void gemm256(const short* __restrict__ Abase, const short* __restrict__ Wbase,
             const float* __restrict__ b0, const float* __restrict__ b1,
             const float* __restrict__ b2,
             void* __restrict__ O0p, void* __restrict__ O1p, void* __restrict__ O2p) {
    __shared__ short As[2][256 * 64];   // 64 KB
    __shared__ short Ws[2][256 * 64];   // 64 KB

    int t = threadIdx.x;
    int z = blockIdx.y;
    const short* A    = Abase + (size_t)z * ((size_t)MM * DMM);
    const short* W    = Wbase + (size_t)z * ((size_t)DMM * DMM);
    const float* bias = (z == 0) ? b0 : (z == 1) ? b1 : b2;
    void* outp        = (z == 0) ? O0p : (z == 1) ? O1p : O2p;

    // nt in high bits: the 4 nt-blocks of one mt land on the same XCD (bid%8 == mt%8):
    // A-slice 512KB + 4 W-panels 2MB fit the 4MB XCD L2.
    int bid = blockIdx.x;
    int mt = bid & 15, nt = bid >> 4;
    int m0 = mt * 256, n0 = nt * 256;

    int lane = t & 63, w = t >> 6;
    int quad = lane >> 4, col = lane & 15;
    int wm = (w >> 2) * 128;   // wave row base (2)
    int wn = (w & 3) * 64;     // wave col base (4)

    float4v acc[8][4];
    #pragma unroll
    for (int i = 0; i < 8; i++)
        #pragma unroll
        for (int j = 0; j < 4; j++) acc[i][j] = (float4v){0, 0, 0, 0};

    // staging: thread t covers (row = chunk*64 + (t>>3), 16B slot (t&7)); source column
    // pre-swizzled so linear LDS dest holds the XOR-swizzled layout.
    int srow = t >> 3;                              // 0..63
    int scol = ((t & 7) ^ (srow & 7)) * 8;          // elements
    const short* Ap = A + (size_t)(m0 + srow) * DMM + scol;
    const short* Wp = W + (size_t)(n0 + srow) * DMM + scol;

    #define STAGE256(bf, tt) do { size_t kk = (size_t)(tt) * 64; \
        ASYNC16(Ap + kk,                        &As[bf][t * 8]); \
        ASYNC16(Ap +  64 * (size_t)DMM + kk,    &As[bf][4096  + t * 8]); \
        ASYNC16(Ap + 128 * (size_t)DMM + kk,    &As[bf][8192  + t * 8]); \
        ASYNC16(Ap + 192 * (size_t)DMM + kk,    &As[bf][12288 + t * 8]); \
        ASYNC16(Wp + kk,                        &Ws[bf][t * 8]); \
        ASYNC16(Wp +  64 * (size_t)DMM + kk,    &Ws[bf][4096  + t * 8]); \
        ASYNC16(Wp + 128 * (size_t)DMM + kk,    &Ws[bf][8192  + t * 8]); \
        ASYNC16(Wp + 192 * (size_t)DMM + kk,    &Ws[bf][12288 + t * 8]); \
    } while (0)

    int c7 = col & 7;   // row&7 for all fragment rows (bases are multiples of 8)

    STAGE256(0, 0);

    for (int it = 0; it < 16; it++) {
        int cur = it & 1;
        if (it < 15) {
            STAGE256(cur ^ 1, it + 1);                       // issue-early: next tile
            asm volatile("s_waitcnt vmcnt(8)" ::: "memory"); // current tile landed
        } else {
            asm volatile("s_waitcnt vmcnt(0)" ::: "memory");
        }
        __builtin_amdgcn_s_barrier();

        // B fragments resident for the whole K-tile (8 x b128, conflict-free)
        short8 bF[4][2];
        #pragma unroll
        for (int j = 0; j < 4; j++) {
            int rB = (wn + 16 * j + col) * 64;
            #pragma unroll
            for (int ks = 0; ks < 2; ks++)
                bF[j][ks] = *(short8*)&Ws[cur][rB + ((((ks << 2) | quad) ^ c7) << 3)];
        }

        #pragma unroll
        for (int p = 0; p < 4; p++) {
            if (p) __builtin_amdgcn_s_barrier();
            short8 aF[2][2];
            #pragma unroll
            for (int u = 0; u < 2; u++) {
                int rA = (wm + 16 * (2 * p + u) + col) * 64;
                #pragma unroll
                for (int ks = 0; ks < 2; ks++)
                    aF[u][ks] = *(short8*)&As[cur][rA + ((((ks << 2) | quad) ^ c7) << 3)];
            }
            __builtin_amdgcn_s_setprio(1);
            #pragma unroll
            for (int ks = 0; ks < 2; ks++)
                #pragma unroll
                for (int u = 0; u < 2; u++)
                    #pragma unroll
                    for (int j = 0; j < 4; j++)
                        acc[2 * p + u][j] = __builtin_amdgcn_mfma_f32_16x16x32_bf16(
                            aF[u][ks], bF[j][ks], acc[2 * p + u][j], 0, 0, 0);
            __builtin_amdgcn_s_setprio(0);
        }
        __builtin_amdgcn_s_barrier();   // WAR: reads of buf[cur] done before next stage
    }
    #undef STAGE256

    #pragma unroll
    for (int i = 0; i < 8; i++) {
        #pragma unroll
        for (int j = 0; j < 4; j++) {
            int n = n0 + wn + 16 * j + col;
            float bn = bias[n];
            #pragma unroll
            for (int r = 0; r < 4; r++) {
                int m = m0 + wm + 16 * i + quad * 4 + r;
                float val = acc[i][j][r] + bn;
                size_t idx;
                if (HEADSPLIT) {
                    int b = m >> 11;
                    int s = m & 2047;
                    int h = n >> 6;
                    int hd = n & 63;
                    idx = (((size_t)b * HH + h) * SS + s) * HDD + hd;
                } else {
                    idx = (size_t)m * DMM + n;
                }
                if (OBF) ((short*)outp)[idx] = f2bf(val);
                else     ((float*)outp)[idx] = val;
            }
        }
    }
}

// ---------------- Wo GEMM: 64x128 tile, 2-phase pipeline, 512 blocks = 2/CU ----------------
// R0's verified 64x128 geometry + R3's verified 2-phase loop. 2 blocks/CU for TLP
// (the 256-block 128x128 version was 1/CU and pure latency-bound at 205 TF).
__global__ __launch_bounds__(256)
void gemm64p(const short* __restrict__ A, const short* __restrict__ W,
             const float* __restrict__ bias, float* __restrict__ out) {
    __shared__ short As[2][64 * 32];    // 8 KB
    __shared__ short Ws[2][128 * 32];   // 16 KB

    int t = threadIdx.x;
    int bid = blockIdx.x;
    int xcd = bid & 7, loc = bid >> 3;    // XCD round-robin
    int nblk = loc & 7, mloc = loc >> 3;  // per-XCD: 8 m-blocks x 8 n-blocks
    int m0 = (xcd * 8 + mloc) * 64;
    int n0 = nblk * 128;

    int lane = t & 63, w = t >> 6;
    int quad = lane >> 4, col = lane & 15;
    int arow0 = (w & 1) * 32;
    int ncol0 = (w >> 1) * 64;

    float4v acc[2][4];
    #pragma unroll
    for (int i = 0; i < 2; i++)
        #pragma unroll
        for (int j = 0; j < 4; j++) acc[i][j] = (float4v){0, 0, 0, 0};

    const short* Apa = A + (size_t)(m0 + (t >> 2)) * DMM + (t & 3) * 8;
    const short* Wp  = W + (size_t)(n0 + (t >> 2)) * DMM + (t & 3) * 8;

    #define STAGEW(bf, tt) do { int kk = (tt) * 32; \
        ASYNC16(Apa + kk,                     &As[bf][t * 8]); \
        ASYNC16(Wp + kk,                      &Ws[bf][t * 8]); \
        ASYNC16(Wp + 64 * (size_t)DMM + kk,   &Ws[bf][2048 + t * 8]); \
    } while (0)

    STAGEW(0, 0);
    asm volatile("s_waitcnt vmcnt(0)" ::: "memory");
    __builtin_amdgcn_s_barrier();

    for (int it = 0; it < 32; it++) {
        int cur = it & 1;
        if (it + 1 < 32) STAGEW(cur ^ 1, it + 1);   // issue next tile's loads FIRST

        short8 aF[2], bF[4];
        #pragma unroll
        for (int i = 0; i < 2; i++)
            aF[i] = *(short8*)&As[cur][(arow0 + 16 * i + col) * 32 + quad * 8];
        #pragma unroll
        for (int j = 0; j < 4; j++)
            bF[j] = *(short8*)&Ws[cur][(ncol0 + 16 * j + col) * 32 + quad * 8];

        __builtin_amdgcn_s_setprio(1);
        #pragma unroll
        for (int i = 0; i < 2; i++)
            #pragma unroll
            for (int j = 0; j < 4; j++)
                acc[i][j] = __builtin_amdgcn_mfma_f32_16x16x32_bf16(aF[i], bF[j], acc[i][j], 0, 0, 0);
        __builtin_amdgcn_s_setprio(0);

        asm volatile("s_waitcnt vmcnt(0)" ::: "memory");
        __builtin_amdgcn_s_barrier();
    }
    #undef STAGEW

    #pragma unroll
    for (int i = 0; i < 2; i++) {
        #pragma unroll
        for (int j = 0; j < 4; j++) {
            int n = n0 + ncol0 + 16 * j + col;
            float bn = bias[n];
            #pragma unroll
            for (int r = 0; r < 4; r++) {
                int m = m0 + arow0 + 16 * i + quad * 4 + r;
                out[(size_t)m * DMM + n] = acc[i][j][r] + bn;
            }
        }
    }
}

// ---------------- banded MFMA attention (XCD-local, swizzled Vt, interval mask) ----------------
// 1D grid 1024: all 16 q-tiles of a (b,h,parity) group land on one XCD (L2 reuse).
// K/V loads for chunk c+1 are issued in registers while chunk c computes (T14).
__global__ __launch_bounds__(256)
void band_attn(const short* __restrict__ qh, const short* __restrict__ kh,
               const short* __restrict__ vh, const int* __restrict__ glist,
               const int* __restrict__ gcount, short* __restrict__ ao) {
    __shared__ short Qs[64 * 72];
    __shared__ short Ks[32 * 72];
    __shared__ short Vt[64 * 40];
    __shared__ short Ps[4 * 16 * 40];
    __shared__ int   gjs[32];

    int t = threadIdx.x;
    int bid = blockIdx.x;
    int xcd = bid & 7, idx = bid >> 3;
    int gl  = idx >> 4;             // 0..7: group slot within XCD
    int qt  = idx & 15;             // q-tile
    int gid = xcd * 8 + gl;         // 0..63 -> (z,h)
    int z   = gid >> 4;
    int h   = gid & 15;
    int b = z >> 1, p = z & 1;
    int qq0 = qt * 64;
    int nG = *gcount;

    const short* Qb = qh + ((size_t)(b * HH + h) * SS) * HDD;
    const short* Kb = kh + ((size_t)(b * HH + h) * SS) * HDD;
    const short* Vb = vh + ((size_t)(b * HH + h) * SS) * HDD;

    int row8 = t >> 3;
    int dim8 = (t & 7) * 8;

    #pragma unroll
    for (int rr = 0; rr < 2; rr++) {
        int row = rr * 32 + row8;
        int i = 2 * (qq0 + row) + p;
        short8 qv = *(const short8*)(Qb + (size_t)i * HDD + dim8);
        *(short8*)&Qs[row * 72 + dim8] = qv;
    }
    if (t < 32) gjs[t] = (t < nG) ? glist[t] : -1000000;
    __syncthreads();

    int lane = t & 63, w = t >> 6;
    int quad = lane >> 4, col = lane & 15;

    short8 qf0 = *(short8*)&Qs[(16 * w + col) * 72 + quad * 8];
    short8 qf1 = *(short8*)&Qs[(16 * w + col) * 72 + 32 + quad * 8];

    float4v O0 = {0,0,0,0}, O1 = {0,0,0,0}, O2 = {0,0,0,0}, O3 = {0,0,0,0};
    float lst[4] = {0.f, 0.f, 0.f, 0.f};

    // prologue: prefetch chunk 0's K/V rows into registers
    short8 kvP, vvP, kvN, vvN;
    {
        int srow = 2 * (qq0 - 256 + row8) + p;
        srow = srow < 0 ? 0 : (srow > SS - 1 ? SS - 1 : srow);
        kvP = *(const short8*)(Kb + (size_t)srow * HDD + dim8);
        vvP = *(const short8*)(Vb + (size_t)srow * HDD + dim8);
    }

    for (int c = 0; c < 19; c++) {
        __syncthreads();
        // write-late: store prefetched chunk c to LDS
        *(short8*)&Ks[row8 * 72 + dim8] = kvP;
        #pragma unroll
        for (int j = 0; j < 8; j++) {
            int d = dim8 + j;
            Vt[VSL(d, row8)] = vvP[j];
        }
        // issue-early: prefetch chunk c+1 (consumed after next barrier)
        if (c < 18) {
            int cn = c + 1;
            int ch0n = qq0 - 256 + cn * 32;
            int srow;
            if (cn < 18) srow = 2 * (ch0n + row8) + p;
            else         srow = (row8 < nG) ? gjs[row8] : 0;
            srow = srow < 0 ? 0 : (srow > SS - 1 ? SS - 1 : srow);
            kvN = *(const short8*)(Kb + (size_t)srow * HDD + dim8);
            vvN = *(const short8*)(Vb + (size_t)srow * HDD + dim8);
        }
        __syncthreads();

        int ch0 = qq0 - 256 + c * 32;

        short8 kA0 = *(short8*)&Ks[col * 72 + quad * 8];
        short8 kA1 = *(short8*)&Ks[col * 72 + 32 + quad * 8];
        short8 kB0 = *(short8*)&Ks[(16 + col) * 72 + quad * 8];
        short8 kB1 = *(short8*)&Ks[(16 + col) * 72 + 32 + quad * 8];
        float4v sA = {0,0,0,0}, sB = {0,0,0,0};
        sA = __builtin_amdgcn_mfma_f32_16x16x32_bf16(qf0, kA0, sA, 0, 0, 0);
        sA = __builtin_amdgcn_mfma_f32_16x16x32_bf16(qf1, kA1, sA, 0, 0, 0);
        sB = __builtin_amdgcn_mfma_f32_16x16x32_bf16(qf0, kB0, sB, 0, 0, 0);
        sB = __builtin_amdgcn_mfma_f32_16x16x32_bf16(qf1, kB1, sB, 0, 0, 0);

        if (c < 18) {
            int nlo = -ch0;            // col >= nlo  (jA >= 0)
            int nhi = 1023 - ch0;      // col <= nhi  (jA < 1024)
            #pragma unroll
            for (int r = 0; r < 4; r++) {
                int qq = qq0 + 16 * w + quad * 4 + r;
                int u  = qq - ch0;
                int lo = max(u - 256, nlo);
                int hi = min(u + 256, nhi);
                bool vA = (col >= lo) && (col <= hi);
                bool vB = (col + 16 >= lo) && (col + 16 <= hi);
                float pa = vA ? exp2f(sA[r] * SCALE2) : 0.f;
                float pb = vB ? exp2f(sB[r] * SCALE2) : 0.f;
                lst[r] += pa + pb;
                Ps[(w * 16 + quad * 4 + r) * 40 + col]      = f2bf(pa);
                Ps[(w * 16 + quad * 4 + r) * 40 + col + 16] = f2bf(pb);
            }
        } else {
            #pragma unroll
            for (int r = 0; r < 4; r++) {
                int qq = qq0 + 16 * w + quad * 4 + r;
                int i = 2 * qq + p;
                int jA = gjs[col], jB = gjs[col + 16];
                int dA = jA - i, dB = jB - i;
                int aA = dA < 0 ? -dA : dA;
                int aB = dB < 0 ? -dB : dB;
                bool vA = (jA >= 0) && !((aA <= 512) && ((dA & 1) == 0));
                bool vB = (jB >= 0) && !((aB <= 512) && ((dB & 1) == 0));
                float pa = vA ? exp2f(sA[r] * SCALE2) : 0.f;
                float pb = vB ? exp2f(sB[r] * SCALE2) : 0.f;
                lst[r] += pa + pb;
                Ps[(w * 16 + quad * 4 + r) * 40 + col]      = f2bf(pa);
                Ps[(w * 16 + quad * 4 + r) * 40 + col + 16] = f2bf(pb);
            }
        }
        asm volatile("s_waitcnt lgkmcnt(0)" ::: "memory");

        short8 pf  = *(short8*)&Ps[(w * 16 + col) * 40 + quad * 8];
        short8 vf0 = *(short8*)&Vt[(col) * 40 + ((quad ^ ((col >> 3) & 3)) << 3)];
        short8 vf1 = *(short8*)&Vt[(16 + col) * 40 + ((quad ^ (((16 + col) >> 3) & 3)) << 3)];
        short8 vf2 = *(short8*)&Vt[(32 + col) * 40 + ((quad ^ (((32 + col) >> 3) & 3)) << 3)];
        short8 vf3 = *(short8*)&Vt[(48 + col) * 40 + ((quad ^ (((48 + col) >> 3) & 3)) << 3)];
        O0 = __builtin_amdgcn_mfma_f32_16x16x32_bf16(pf, vf0, O0, 0, 0, 0);
        O1 = __builtin_amdgcn_mfma_f32_16x16x32_bf16(pf, vf1, O1, 0, 0, 0);
        O2 = __builtin_amdgcn_mfma_f32_16x16x32_bf16(pf, vf2, O2, 0, 0, 0);
        O3 = __builtin_amdgcn_mfma_f32_16x16x32_bf16(pf, vf3, O3, 0, 0, 0);

        kvP = kvN; vvP = vvN;
    }

    #pragma unroll
    for (int r = 0; r < 4; r++) {
        float l = lst[r];
        #pragma unroll
        for (int mk = 1; mk < 16; mk <<= 1) l += __shfl_xor(l, mk);
        float inv = 1.0f / l;
        int q = 16 * w + quad * 4 + r;
        int i = 2 * (qq0 + q) + p;
        short* dst = ao + ((size_t)b * SS + i) * DMM + h * HDD;
        dst[col]      = f2bf(O0[r] * inv);
        dst[col + 16] = f2bf(O1[r] * inv);
        dst[col + 32] = f2bf(O2[r] * inv);
        dst[col + 48] = f2bf(O3[r] * inv);
    }
}

// ---------------- global rows: split-K MFMA partials (no-max softmax) ----------------
__global__ __launch_bounds__(256)
void global_part(const short* __restrict__ qh, const short* __restrict__ kh,
                 const short* __restrict__ vh, const int* __restrict__ glist,
                 const int* __restrict__ gcount,
                 float* __restrict__ pl, float* __restrict__ pO) {
    __shared__ short Qs[32 * 72];
    __shared__ short Ks[2][32 * 72];
    __shared__ short Vt[2][64 * 40];
    __shared__ short Ps[4 * 16 * 40];

    int t = threadIdx.x;
    int s = blockIdx.x, h = blockIdx.y, b = blockIdx.z;
    int nG = *gcount;

    const short* Qb = qh + ((size_t)(b * HH + h) * SS) * HDD;
    const short* Kb = kh + ((size_t)(b * HH + h) * SS) * HDD;
    const short* Vb = vh + ((size_t)(b * HH + h) * SS) * HDD;

    int row8 = t >> 3, dim8 = (t & 7) * 8;
    {
        int cq = row8 < nG ? row8 : 0;
        int src = glist[cq];
        short8 qv = *(const short8*)(Qb + (size_t)src * HDD + dim8);
        *(short8*)&Qs[row8 * 72 + dim8] = qv;
    }
    __syncthreads();

    int lane = t & 63, w = t >> 6;
    int quad = lane >> 4, col = lane & 15;
    int g = w >> 1, qt = w & 1;

    short8 qf0 = *(short8*)&Qs[(qt * 16 + col) * 72 + quad * 8];
    short8 qf1 = *(short8*)&Qs[(qt * 16 + col) * 72 + 32 + quad * 8];

    float4v O0 = {0,0,0,0}, O1 = {0,0,0,0}, O2 = {0,0,0,0}, O3 = {0,0,0,0};
    float lst[4] = {0.f, 0.f, 0.f, 0.f};

    int js0 = s * 256;
    for (int it = 0; it < 4; it++) {
        __syncthreads();
        int r64 = t >> 2, dimb = (t & 3) * 16;
        int j = js0 + it * 64 + r64;
        const short* kp = Kb + (size_t)j * HDD + dimb;
        const short* vp = Vb + (size_t)j * HDD + dimb;
        short8 k0 = *(const short8*)kp, k1 = *(const short8*)(kp + 8);
        short8 v0 = *(const short8*)vp, v1 = *(const short8*)(vp + 8);
        int half = r64 >> 5, r32 = r64 & 31;
        *(short8*)&Ks[half][r32 * 72 + dimb]     = k0;
        *(short8*)&Ks[half][r32 * 72 + dimb + 8] = k1;
        #pragma unroll
        for (int u = 0; u < 8; u++) {
            int d = dimb + u;
            Vt[half][VSL(d, r32)] = v0[u];
        }
        #pragma unroll
        for (int u = 0; u < 8; u++) {
            int d = dimb + 8 + u;
            Vt[half][VSL(d, r32)] = v1[u];
        }
        __syncthreads();

        short8 kA0 = *(short8*)&Ks[g][col * 72 + quad * 8];
        short8 kA1 = *(short8*)&Ks[g][col * 72 + 32 + quad * 8];
        short8 kB0 = *(short8*)&Ks[g][(16 + col) * 72 + quad * 8];
        short8 kB1 = *(short8*)&Ks[g][(16 + col) * 72 + 32 + quad * 8];
        float4v sA = {0,0,0,0}, sB = {0,0,0,0};
        sA = __builtin_amdgcn_mfma_f32_16x16x32_bf16(qf0, kA0, sA, 0, 0, 0);
        sA = __builtin_amdgcn_mfma_f32_16x16x32_bf16(qf1, kA1, sA, 0, 0, 0);
        sB = __builtin_amdgcn_mfma_f32_16x16x32_bf16(qf0, kB0, sB, 0, 0, 0);
        sB = __builtin_amdgcn_mfma_f32_16x16x32_bf16(qf1, kB1, sB, 0, 0, 0);

        #pragma unroll
        for (int r = 0; r < 4; r++) {
            float pa = exp2f(sA[r] * SCALE2);
            float pb = exp2f(sB[r] * SCALE2);
            lst[r] += pa + pb;
            Ps[(w * 16 + quad * 4 + r) * 40 + col]      = f2bf(pa);
            Ps[(w * 16 + quad * 4 + r) * 40 + col + 16] = f2bf(pb);
        }
        asm volatile("s_waitcnt lgkmcnt(0)" ::: "memory");

        short8 pf  = *(short8*)&Ps[(w * 16 + col) * 40 + quad * 8];
        short8 vf0 = *(short8*)&Vt[g][(col) * 40 + ((quad ^ ((col >> 3) & 3)) << 3)];
        short8 vf1 = *(short8*)&Vt[g][(16 + col) * 40 + ((quad ^ (((16 + col) >> 3) & 3)) << 3)];
        short8 vf2 = *(short8*)&Vt[g][(32 + col) * 40 + ((quad ^ (((32 + col) >> 3) & 3)) << 3)];
        short8 vf3 = *(short8*)&Vt[g][(48 + col) * 40 + ((quad ^ (((48 + col) >> 3) & 3)) << 3)];
        O0 = __builtin_amdgcn_mfma_f32_16x16x32_bf16(pf, vf0, O0, 0, 0, 0);
        O1 = __builtin_amdgcn_mfma_f32_16x16x32_bf16(pf, vf1, O1, 0, 0, 0);
        O2 = __builtin_amdgcn_mfma_f32_16x16x32_bf16(pf, vf2, O2, 0, 0, 0);
        O3 = __builtin_amdgcn_mfma_f32_16x16x32_bf16(pf, vf3, O3, 0, 0, 0);
    }

    int sp = s * 2 + g;
    size_t base = ((size_t)(b * HH + h) * 16 + sp) * 32;
    #pragma unroll
    for (int r = 0; r < 4; r++) {
        float l = lst[r];
        #pragma unroll
        for (int mk = 1; mk < 16; mk <<= 1) l += __shfl_xor(l, mk);
        int q = qt * 16 + quad * 4 + r;
        if (col == 0) pl[base + q] = l;
        float* Od = pO + (base + q) * 64;
        Od[col]      = O0[r];
        Od[col + 16] = O1[r];
        Od[col + 32] = O2[r];
        Od[col + 48] = O3[r];
    }
}

// ---------------- merge 16 partials per (b,h): plain sums ----------------
__global__ __launch_bounds__(256)
void global_merge(const float* __restrict__ pl, const float* __restrict__ pO,
                  const int* __restrict__ glist, const int* __restrict__ gcount,
                  short* __restrict__ ao) {
    int h = blockIdx.x, b = blockIdx.y;
    int t = threadIdx.x;
    int d = t & 63, qg = t >> 6;
    int nG = *gcount;
    size_t bh = ((size_t)(b * HH + h) * 16) * 32;

    for (int q = qg; q < nG; q += 4) {
        float L = 0.f, acc = 0.f;
        #pragma unroll
        for (int sp = 0; sp < 16; sp++) {
            L   += pl[bh + sp * 32 + q];
            acc += pO[(bh + sp * 32 + q) * 64 + d];
        }
        int i = glist[q];
        ao[((size_t)b * SS + i) * DMM + h * HDD + d] = f2bf(acc / L);
    }
}

extern "C" void kernel_launch(void* const* d_in, const int* in_sizes, int n_in,
                              void* d_out, int out_size, void* d_ws, size_t ws_size,
                              hipStream_t stream) {
    const float* q  = (const float*)d_in[0];
    const float* k  = (const float*)d_in[1];
    const float* v  = (const float*)d_in[2];
    const float* Wq = (const float*)d_in[3];
    const float* Wk = (const float*)d_in[4];
    const float* Wv = (const float*)d_in[5];
    const float* Wo = (const float*)d_in[6];
    const float* bq = (const float*)d_in[7];
    const float* bk = (const float*)d_in[8];
    const float* bv = (const float*)d_in[9];
    const float* bo = (const float*)d_in[10];
    const int* gidx = (const int*)d_in[11];
    float* out = (float*)d_out;

    // ws (64.03 MB): 32KB hdr | qh,kh,vh,ao bf16 8MB ea | wbf 8MB | abf 24MB (aliased by pl+pO)
    const size_t NE = (size_t)BB * SS * DMM;   // 4M
    const size_t WE = (size_t)DMM * DMM;       // 1M
    int*   g      = (int*)d_ws;
    int*   glist  = g + SS;
    int*   gcount = glist + SS;
    short* qh     = (short*)((char*)d_ws + 32768);
    short* kh     = qh + NE;
    short* vh     = kh + NE;
    short* ao     = vh + NE;
    short* wbf    = ao + NE;
    short* wo     = wbf + 3 * WE;
    short* abf    = wbf + 4 * WE;          // dead after QKV gemm
    float* pl     = (float*)abf;           // alias: written by global_part (later)
    float* pO     = pl + 16384;

    setup_globals<<<1, 256, 0, stream>>>(gidx, g, glist, gcount);

    dim3 gc(2048, 7);
    convert_all<<<gc, 256, 0, stream>>>(q, k, v, Wq, Wk, Wv, Wo, abf, wbf);

    dim3 gq(64, 3);    // batched QKV, 256x256 tiles: 192 blocks, 512 threads
    gemm256<1, 1><<<gq, 512, 0, stream>>>(abf, wbf, bq, bk, bv, qh, kh, vh);

    band_attn<<<1024, 256, 0, stream>>>(qh, kh, vh, glist, gcount, ao);

    dim3 gp(8, HH, BB);
    global_part<<<gp, 256, 0, stream>>>(qh, kh, vh, glist, gcount, pl, pO);

    dim3 gm(HH, BB);
    global_merge<<<gm, 256, 0, stream>>>(pl, pO, glist, gcount, ao);

    gemm64p<<<512, 256, 0, stream>>>(ao, wo, bo, out);   // Wo: 64x128 tiles, 2/CU
}

// Round 5
// 215.572 us; speedup vs baseline: 1.1164x; 1.0776x over previous
//
#include <hip/hip_runtime.h>
#include <hip/hip_bf16.h>
#include <math.h>

#define BB 2
#define SS 2048
#define DMM 1024
#define HH 16
#define HDD 64
#define NGLOB 32
#define MM 4096   // B*S
#define SCALE2 0.18033688f   // 0.125 * log2(e): exp(s/8) == exp2(s*SCALE2)

typedef __attribute__((ext_vector_type(8))) short short8;
typedef __attribute__((ext_vector_type(4))) float float4v;

__device__ __forceinline__ short f2bf(float f) {
    union { float f; unsigned u; } x; x.f = f;
    unsigned r = (x.u + 0x7fffu + ((x.u >> 16) & 1u)) >> 16;  // RNE
    return (short)r;
}

// async 16B global->LDS (m97 path). LDS dest = wave-uniform base + lane*16.
#define ASYNC16(gp, lp) __builtin_amdgcn_global_load_lds( \
    (__attribute__((address_space(1))) void*)(gp), \
    (__attribute__((address_space(3))) void*)(lp), 16, 0, 0)

// Vt slot swizzle: key-chunk XORed with dim-derived tag -> breaks the
// dim*stride==0 (mod 32 banks) collapse on transpose stores (16-way -> 4-way).
#define VSL(dim, key) ((dim) * 40 + (((((key) >> 3) ^ (((dim) >> 3) & 3)) << 3) | ((key) & 7)))

// ---------------- convert fp32->bf16 (q,k,v,4 weights) + fused setup_globals (z==7) ----------------
__global__ __launch_bounds__(256)
void convert_all(const float* __restrict__ q, const float* __restrict__ k,
                 const float* __restrict__ v,
                 const float* __restrict__ w0, const float* __restrict__ w1,
                 const float* __restrict__ w2, const float* __restrict__ w3,
                 short* __restrict__ abf, short* __restrict__ wbf,
                 const int* __restrict__ gidx, int* __restrict__ g,
                 int* __restrict__ glist, int* __restrict__ gcount) {
    int z = blockIdx.y;
    int t = threadIdx.x;
    if (z == 7) {                      // fused setup_globals: 1 real block
        if (blockIdx.x != 0) return;
        for (int i = t; i < SS; i += 256) g[i] = 0;
        if (t == 0) *gcount = 0;
        __syncthreads();
        if (t < NGLOB) {
            int j = gidx[t];
            if (j >= 0 && j < SS) g[j] = 1;
        }
        __syncthreads();
        for (int j = t; j < SS; j += 256) {
            if (g[j]) {
                int p = atomicAdd(gcount, 1);
                glist[p] = j;
            }
        }
        return;
    }
    const float* src;
    short* dst;
    size_t n;
    if (z < 3) {
        src = (z == 0) ? q : (z == 1) ? k : v;
        dst = abf + (size_t)z * ((size_t)MM * DMM);
        n = (size_t)MM * DMM;
    } else {
        int y = z - 3;
        src = (y == 0) ? w0 : (y == 1) ? w1 : (y == 2) ? w2 : w3;
        dst = wbf + (size_t)y * ((size_t)DMM * DMM);
        n = (size_t)DMM * DMM;
    }
    size_t i = ((size_t)blockIdx.x * 256 + t) * 8;
    if (i >= n) return;
    float4 a = *(const float4*)(src + i);
    float4 b = *(const float4*)(src + i + 4);
    short8 s;
    s[0]=f2bf(a.x); s[1]=f2bf(a.y); s[2]=f2bf(a.z); s[3]=f2bf(a.w);
    s[4]=f2bf(b.x); s[5]=f2bf(b.y); s[6]=f2bf(b.z); s[7]=f2bf(b.w);
    *(short8*)(dst + i) = s;
}

// ---------------- 256x256/BK=64 MFMA GEMM: T2 swizzle + counted vmcnt + T5 (R4-verified) ---------
template<int OBF, int HEADSPLIT>
__global__ __launch_bounds__(512, 2)
void gemm256(const short* __restrict__ Abase, const short* __restrict__ Wbase,
             const float* __restrict__ b0, const float* __restrict__ b1,
             const float* __restrict__ b2,
             void* __restrict__ O0p, void* __restrict__ O1p, void* __restrict__ O2p) {
    __shared__ short As[2][256 * 64];   // 64 KB
    __shared__ short Ws[2][256 * 64];   // 64 KB

    int t = threadIdx.x;
    int z = blockIdx.y;
    const short* A    = Abase + (size_t)z * ((size_t)MM * DMM);
    const short* W    = Wbase + (size_t)z * ((size_t)DMM * DMM);
    const float* bias = (z == 0) ? b0 : (z == 1) ? b1 : b2;
    void* outp        = (z == 0) ? O0p : (z == 1) ? O1p : O2p;

    int bid = blockIdx.x;
    int mt = bid & 15, nt = bid >> 4;   // bid%8 == mt%8: nt-blocks of one mt share an XCD
    int m0 = mt * 256, n0 = nt * 256;

    int lane = t & 63, w = t >> 6;
    int quad = lane >> 4, col = lane & 15;
    int wm = (w >> 2) * 128;
    int wn = (w & 3) * 64;

    float4v acc[8][4];
    #pragma unroll
    for (int i = 0; i < 8; i++)
        #pragma unroll
        for (int j = 0; j < 4; j++) acc[i][j] = (float4v){0, 0, 0, 0};

    int srow = t >> 3;
    int scol = ((t & 7) ^ (srow & 7)) * 8;
    const short* Ap = A + (size_t)(m0 + srow) * DMM + scol;
    const short* Wp = W + (size_t)(n0 + srow) * DMM + scol;

    #define STAGE256(bf, tt) do { size_t kk = (size_t)(tt) * 64; \
        ASYNC16(Ap + kk,                        &As[bf][t * 8]); \
        ASYNC16(Ap +  64 * (size_t)DMM + kk,    &As[bf][4096  + t * 8]); \
        ASYNC16(Ap + 128 * (size_t)DMM + kk,    &As[bf][8192  + t * 8]); \
        ASYNC16(Ap + 192 * (size_t)DMM + kk,    &As[bf][12288 + t * 8]); \
        ASYNC16(Wp + kk,                        &Ws[bf][t * 8]); \
        ASYNC16(Wp +  64 * (size_t)DMM + kk,    &Ws[bf][4096  + t * 8]); \
        ASYNC16(Wp + 128 * (size_t)DMM + kk,    &Ws[bf][8192  + t * 8]); \
        ASYNC16(Wp + 192 * (size_t)DMM + kk,    &Ws[bf][12288 + t * 8]); \
    } while (0)

    int c7 = col & 7;

    STAGE256(0, 0);

    for (int it = 0; it < 16; it++) {
        int cur = it & 1;
        if (it < 15) {
            STAGE256(cur ^ 1, it + 1);
            asm volatile("s_waitcnt vmcnt(8)" ::: "memory");
        } else {
            asm volatile("s_waitcnt vmcnt(0)" ::: "memory");
        }
        __builtin_amdgcn_s_barrier();

        short8 bF[4][2];
        #pragma unroll
        for (int j = 0; j < 4; j++) {
            int rB = (wn + 16 * j + col) * 64;
            #pragma unroll
            for (int ks = 0; ks < 2; ks++)
                bF[j][ks] = *(short8*)&Ws[cur][rB + ((((ks << 2) | quad) ^ c7) << 3)];
        }

        #pragma unroll
        for (int p = 0; p < 4; p++) {
            if (p) __builtin_amdgcn_s_barrier();
            short8 aF[2][2];
            #pragma unroll
            for (int u = 0; u < 2; u++) {
                int rA = (wm + 16 * (2 * p + u) + col) * 64;
                #pragma unroll
                for (int ks = 0; ks < 2; ks++)
                    aF[u][ks] = *(short8*)&As[cur][rA + ((((ks << 2) | quad) ^ c7) << 3)];
            }
            __builtin_amdgcn_s_setprio(1);
            #pragma unroll
            for (int ks = 0; ks < 2; ks++)
                #pragma unroll
                for (int u = 0; u < 2; u++)
                    #pragma unroll
                    for (int j = 0; j < 4; j++)
                        acc[2 * p + u][j] = __builtin_amdgcn_mfma_f32_16x16x32_bf16(
                            aF[u][ks], bF[j][ks], acc[2 * p + u][j], 0, 0, 0);
            __builtin_amdgcn_s_setprio(0);
        }
        __builtin_amdgcn_s_barrier();
    }
    #undef STAGE256

    #pragma unroll
    for (int i = 0; i < 8; i++) {
        #pragma unroll
        for (int j = 0; j < 4; j++) {
            int n = n0 + wn + 16 * j + col;
            float bn = bias[n];
            #pragma unroll
            for (int r = 0; r < 4; r++) {
                int m = m0 + wm + 16 * i + quad * 4 + r;
                float val = acc[i][j][r] + bn;
                size_t idx;
                if (HEADSPLIT) {
                    int b = m >> 11;
                    int s = m & 2047;
                    int h = n >> 6;
                    int hd = n & 63;
                    idx = (((size_t)b * HH + h) * SS + s) * HDD + hd;
                } else {
                    idx = (size_t)m * DMM + n;
                }
                if (OBF) ((short*)outp)[idx] = f2bf(val);
                else     ((float*)outp)[idx] = val;
            }
        }
    }
}

// ---------------- Wo GEMM: 128x128/BK=64, 512 thr, T2 swizzle + counted vmcnt + T5 --------------
// 256 blocks = full CU coverage (the N=1024 output limits the grid; 128x128 is the largest
// tile that still covers all CUs). Same verified swizzle/pipeline algebra as gemm256.
__global__ __launch_bounds__(512, 2)
void gemm128wo(const short* __restrict__ A, const short* __restrict__ W,
               const float* __restrict__ bias, float* __restrict__ out) {
    __shared__ short As[2][128 * 64];   // 32 KB
    __shared__ short Ws[2][128 * 64];   // 32 KB

    int t = threadIdx.x;
    int bid = blockIdx.x;
    int mt = bid & 31, nt = bid >> 5;   // bid%8 == mt%8: nt-blocks of one mt share an XCD
    int m0 = mt * 128, n0 = nt * 128;

    int lane = t & 63, w = t >> 6;
    int quad = lane >> 4, col = lane & 15;
    int wm = (w >> 2) * 64;    // 2 wave-rows
    int wn = (w & 3) * 32;     // 4 wave-cols

    float4v acc[4][2];
    #pragma unroll
    for (int i = 0; i < 4; i++)
        #pragma unroll
        for (int j = 0; j < 2; j++) acc[i][j] = (float4v){0, 0, 0, 0};

    int srow = t >> 3;                       // 0..63
    int scol = ((t & 7) ^ (srow & 7)) * 8;   // pre-swizzled source column
    const short* Ap = A + (size_t)(m0 + srow) * DMM + scol;
    const short* Wp = W + (size_t)(n0 + srow) * DMM + scol;

    #define STAGEWO(bf, tt) do { size_t kk = (size_t)(tt) * 64; \
        ASYNC16(Ap + kk,                      &As[bf][t * 8]); \
        ASYNC16(Ap + 64 * (size_t)DMM + kk,   &As[bf][4096 + t * 8]); \
        ASYNC16(Wp + kk,                      &Ws[bf][t * 8]); \
        ASYNC16(Wp + 64 * (size_t)DMM + kk,   &Ws[bf][4096 + t * 8]); \
    } while (0)

    int c7 = col & 7;

    STAGEWO(0, 0);

    for (int it = 0; it < 16; it++) {
        int cur = it & 1;
        if (it < 15) {
            STAGEWO(cur ^ 1, it + 1);
            asm volatile("s_waitcnt vmcnt(4)" ::: "memory");   // current tile's 4 landed
        } else {
            asm volatile("s_waitcnt vmcnt(0)" ::: "memory");
        }
        __builtin_amdgcn_s_barrier();

        short8 bF[2][2];
        #pragma unroll
        for (int j = 0; j < 2; j++) {
            int rB = (wn + 16 * j + col) * 64;
            #pragma unroll
            for (int ks = 0; ks < 2; ks++)
                bF[j][ks] = *(short8*)&Ws[cur][rB + ((((ks << 2) | quad) ^ c7) << 3)];
        }

        #pragma unroll
        for (int p = 0; p < 2; p++) {
            if (p) __builtin_amdgcn_s_barrier();
            short8 aF[2][2];
            #pragma unroll
            for (int u = 0; u < 2; u++) {
                int rA = (wm + 16 * (2 * p + u) + col) * 64;
                #pragma unroll
                for (int ks = 0; ks < 2; ks++)
                    aF[u][ks] = *(short8*)&As[cur][rA + ((((ks << 2) | quad) ^ c7) << 3)];
            }
            __builtin_amdgcn_s_setprio(1);
            #pragma unroll
            for (int ks = 0; ks < 2; ks++)
                #pragma unroll
                for (int u = 0; u < 2; u++)
                    #pragma unroll
                    for (int j = 0; j < 2; j++)
                        acc[2 * p + u][j] = __builtin_amdgcn_mfma_f32_16x16x32_bf16(
                            aF[u][ks], bF[j][ks], acc[2 * p + u][j], 0, 0, 0);
            __builtin_amdgcn_s_setprio(0);
        }
        __builtin_amdgcn_s_barrier();
    }
    #undef STAGEWO

    #pragma unroll
    for (int i = 0; i < 4; i++) {
        #pragma unroll
        for (int j = 0; j < 2; j++) {
            int n = n0 + wn + 16 * j + col;
            float bn = bias[n];
            #pragma unroll
            for (int r = 0; r < 4; r++) {
                int m = m0 + wm + 16 * i + quad * 4 + r;
                out[(size_t)m * DMM + n] = acc[i][j][r] + bn;
            }
        }
    }
}

// ---------------- fused attention: band (blocks 0..1023) + global_part (1024..1279) ----------------
// band and global_part are data-independent (both read qh/kh/vh, write disjoint outputs);
// fusing lets global_part's 256 blocks fill CUs during band's tail and removes a dispatch.
// Shared memory is a union (29184 B = max of the two branches), aliased per branch.
__global__ __launch_bounds__(256)
void attn_fused(const short* __restrict__ qh, const short* __restrict__ kh,
                const short* __restrict__ vh, const int* __restrict__ glist,
                const int* __restrict__ gcount, short* __restrict__ ao,
                float* __restrict__ pl, float* __restrict__ pO) {
    __shared__ __align__(16) char smem[29184];
    int t = threadIdx.x;
    int bid = blockIdx.x;
    int nG = *gcount;

    if (bid < 1024) {
        // ---------- banded attention (XCD-local, swizzled Vt, interval mask, T14 prefetch) -------
        short* Qs = (short*)smem;            // 64*72
        short* Ks = Qs + 64 * 72;            // 32*72
        short* Vt = Ks + 32 * 72;            // 64*40
        short* Ps = Vt + 64 * 40;            // 4*16*40
        int*   gjs = (int*)(Ps + 4 * 16 * 40);  // 32 ints

        int xcd = bid & 7, idx = bid >> 3;
        int gl  = idx >> 4;
        int qt  = idx & 15;
        int gid = xcd * 8 + gl;
        int z   = gid >> 4;
        int h   = gid & 15;
        int b = z >> 1, p = z & 1;
        int qq0 = qt * 64;

        const short* Qb = qh + ((size_t)(b * HH + h) * SS) * HDD;
        const short* Kb = kh + ((size_t)(b * HH + h) * SS) * HDD;
        const short* Vb = vh + ((size_t)(b * HH + h) * SS) * HDD;

        int row8 = t >> 3;
        int dim8 = (t & 7) * 8;

        #pragma unroll
        for (int rr = 0; rr < 2; rr++) {
            int row = rr * 32 + row8;
            int i = 2 * (qq0 + row) + p;
            short8 qv = *(const short8*)(Qb + (size_t)i * HDD + dim8);
            *(short8*)&Qs[row * 72 + dim8] = qv;
        }
        if (t < 32) gjs[t] = (t < nG) ? glist[t] : -1000000;
        __syncthreads();

        int lane = t & 63, w = t >> 6;
        int quad = lane >> 4, col = lane & 15;

        short8 qf0 = *(short8*)&Qs[(16 * w + col) * 72 + quad * 8];
        short8 qf1 = *(short8*)&Qs[(16 * w + col) * 72 + 32 + quad * 8];

        float4v O0 = {0,0,0,0}, O1 = {0,0,0,0}, O2 = {0,0,0,0}, O3 = {0,0,0,0};
        float lst[4] = {0.f, 0.f, 0.f, 0.f};

        short8 kvP, vvP, kvN, vvN;
        {
            int srow = 2 * (qq0 - 256 + row8) + p;
            srow = srow < 0 ? 0 : (srow > SS - 1 ? SS - 1 : srow);
            kvP = *(const short8*)(Kb + (size_t)srow * HDD + dim8);
            vvP = *(const short8*)(Vb + (size_t)srow * HDD + dim8);
        }

        for (int c = 0; c < 19; c++) {
            __syncthreads();
            *(short8*)&Ks[row8 * 72 + dim8] = kvP;
            #pragma unroll
            for (int j = 0; j < 8; j++) {
                int d = dim8 + j;
                Vt[VSL(d, row8)] = vvP[j];
            }
            if (c < 18) {
                int cn = c + 1;
                int ch0n = qq0 - 256 + cn * 32;
                int srow;
                if (cn < 18) srow = 2 * (ch0n + row8) + p;
                else         srow = (row8 < nG) ? gjs[row8] : 0;
                srow = srow < 0 ? 0 : (srow > SS - 1 ? SS - 1 : srow);
                kvN = *(const short8*)(Kb + (size_t)srow * HDD + dim8);
                vvN = *(const short8*)(Vb + (size_t)srow * HDD + dim8);
            }
            __syncthreads();

            int ch0 = qq0 - 256 + c * 32;

            short8 kA0 = *(short8*)&Ks[col * 72 + quad * 8];
            short8 kA1 = *(short8*)&Ks[col * 72 + 32 + quad * 8];
            short8 kB0 = *(short8*)&Ks[(16 + col) * 72 + quad * 8];
            short8 kB1 = *(short8*)&Ks[(16 + col) * 72 + 32 + quad * 8];
            float4v sA = {0,0,0,0}, sB = {0,0,0,0};
            sA = __builtin_amdgcn_mfma_f32_16x16x32_bf16(qf0, kA0, sA, 0, 0, 0);
            sA = __builtin_amdgcn_mfma_f32_16x16x32_bf16(qf1, kA1, sA, 0, 0, 0);
            sB = __builtin_amdgcn_mfma_f32_16x16x32_bf16(qf0, kB0, sB, 0, 0, 0);
            sB = __builtin_amdgcn_mfma_f32_16x16x32_bf16(qf1, kB1, sB, 0, 0, 0);

            if (c < 18) {
                int nlo = -ch0;
                int nhi = 1023 - ch0;
                #pragma unroll
                for (int r = 0; r < 4; r++) {
                    int qq = qq0 + 16 * w + quad * 4 + r;
                    int u  = qq - ch0;
                    int lo = max(u - 256, nlo);
                    int hi = min(u + 256, nhi);
                    bool vA = (col >= lo) && (col <= hi);
                    bool vB = (col + 16 >= lo) && (col + 16 <= hi);
                    float pa = vA ? exp2f(sA[r] * SCALE2) : 0.f;
                    float pb = vB ? exp2f(sB[r] * SCALE2) : 0.f;
                    lst[r] += pa + pb;
                    Ps[(w * 16 + quad * 4 + r) * 40 + col]      = f2bf(pa);
                    Ps[(w * 16 + quad * 4 + r) * 40 + col + 16] = f2bf(pb);
                }
            } else {
                #pragma unroll
                for (int r = 0; r < 4; r++) {
                    int qq = qq0 + 16 * w + quad * 4 + r;
                    int i = 2 * qq + p;
                    int jA = gjs[col], jB = gjs[col + 16];
                    int dA = jA - i, dB = jB - i;
                    int aA = dA < 0 ? -dA : dA;
                    int aB = dB < 0 ? -dB : dB;
                    bool vA = (jA >= 0) && !((aA <= 512) && ((dA & 1) == 0));
                    bool vB = (jB >= 0) && !((aB <= 512) && ((dB & 1) == 0));
                    float pa = vA ? exp2f(sA[r] * SCALE2) : 0.f;
                    float pb = vB ? exp2f(sB[r] * SCALE2) : 0.f;
                    lst[r] += pa + pb;
                    Ps[(w * 16 + quad * 4 + r) * 40 + col]      = f2bf(pa);
                    Ps[(w * 16 + quad * 4 + r) * 40 + col + 16] = f2bf(pb);
                }
            }
            asm volatile("s_waitcnt lgkmcnt(0)" ::: "memory");

            short8 pf  = *(short8*)&Ps[(w * 16 + col) * 40 + quad * 8];
            short8 vf0 = *(short8*)&Vt[(col) * 40 + ((quad ^ ((col >> 3) & 3)) << 3)];
            short8 vf1 = *(short8*)&Vt[(16 + col) * 40 + ((quad ^ (((16 + col) >> 3) & 3)) << 3)];
            short8 vf2 = *(short8*)&Vt[(32 + col) * 40 + ((quad ^ (((32 + col) >> 3) & 3)) << 3)];
            short8 vf3 = *(short8*)&Vt[(48 + col) * 40 + ((quad ^ (((48 + col) >> 3) & 3)) << 3)];
            O0 = __builtin_amdgcn_mfma_f32_16x16x32_bf16(pf, vf0, O0, 0, 0, 0);
            O1 = __builtin_amdgcn_mfma_f32_16x16x32_bf16(pf, vf1, O1, 0, 0, 0);
            O2 = __builtin_amdgcn_mfma_f32_16x16x32_bf16(pf, vf2, O2, 0, 0, 0);
            O3 = __builtin_amdgcn_mfma_f32_16x16x32_bf16(pf, vf3, O3, 0, 0, 0);

            kvP = kvN; vvP = vvN;
        }

        #pragma unroll
        for (int r = 0; r < 4; r++) {
            float l = lst[r];
            #pragma unroll
            for (int mk = 1; mk < 16; mk <<= 1) l += __shfl_xor(l, mk);
            float inv = 1.0f / l;
            int q = 16 * w + quad * 4 + r;
            int i = 2 * (qq0 + q) + p;
            short* dst = ao + ((size_t)b * SS + i) * DMM + h * HDD;
            dst[col]      = f2bf(O0[r] * inv);
            dst[col + 16] = f2bf(O1[r] * inv);
            dst[col + 32] = f2bf(O2[r] * inv);
            dst[col + 48] = f2bf(O3[r] * inv);
        }
    } else {
        // ---------- global rows: split-K MFMA partials (no-max softmax) ----------
        short* Qs  = (short*)smem;            // 32*72
        short* Ksf = Qs + 32 * 72;            // 2 x 32*72
        short* Vtf = Ksf + 2 * 32 * 72;       // 2 x 64*40
        short* Ps  = Vtf + 2 * 64 * 40;       // 4*16*40

        int r0 = bid - 1024;
        int s = r0 & 7, h = (r0 >> 3) & 15, b = r0 >> 7;

        const short* Qb = qh + ((size_t)(b * HH + h) * SS) * HDD;
        const short* Kb = kh + ((size_t)(b * HH + h) * SS) * HDD;
        const short* Vb = vh + ((size_t)(b * HH + h) * SS) * HDD;

        int row8 = t >> 3, dim8 = (t & 7) * 8;
        {
            int cq = row8 < nG ? row8 : 0;
            int src = glist[cq];
            short8 qv = *(const short8*)(Qb + (size_t)src * HDD + dim8);
            *(short8*)&Qs[row8 * 72 + dim8] = qv;
        }
        __syncthreads();

        int lane = t & 63, w = t >> 6;
        int quad = lane >> 4, col = lane & 15;
        int g = w >> 1, qt = w & 1;

        short8 qf0 = *(short8*)&Qs[(qt * 16 + col) * 72 + quad * 8];
        short8 qf1 = *(short8*)&Qs[(qt * 16 + col) * 72 + 32 + quad * 8];

        float4v O0 = {0,0,0,0}, O1 = {0,0,0,0}, O2 = {0,0,0,0}, O3 = {0,0,0,0};
        float lst[4] = {0.f, 0.f, 0.f, 0.f};

        int js0 = s * 256;
        for (int it = 0; it < 4; it++) {
            __syncthreads();
            int r64 = t >> 2, dimb = (t & 3) * 16;
            int j = js0 + it * 64 + r64;
            const short* kp = Kb + (size_t)j * HDD + dimb;
            const short* vp = Vb + (size_t)j * HDD + dimb;
            short8 k0 = *(const short8*)kp, k1 = *(const short8*)(kp + 8);
            short8 v0 = *(const short8*)vp, v1 = *(const short8*)(vp + 8);
            int half = r64 >> 5, r32 = r64 & 31;
            short* Ksh = Ksf + half * (32 * 72);
            short* Vth = Vtf + half * (64 * 40);
            *(short8*)&Ksh[r32 * 72 + dimb]     = k0;
            *(short8*)&Ksh[r32 * 72 + dimb + 8] = k1;
            #pragma unroll
            for (int u = 0; u < 8; u++) {
                int d = dimb + u;
                Vth[VSL(d, r32)] = v0[u];
            }
            #pragma unroll
            for (int u = 0; u < 8; u++) {
                int d = dimb + 8 + u;
                Vth[VSL(d, r32)] = v1[u];
            }
            __syncthreads();

            short* Ksg = Ksf + g * (32 * 72);
            short* Vtg = Vtf + g * (64 * 40);
            short8 kA0 = *(short8*)&Ksg[col * 72 + quad * 8];
            short8 kA1 = *(short8*)&Ksg[col * 72 + 32 + quad * 8];
            short8 kB0 = *(short8*)&Ksg[(16 + col) * 72 + quad * 8];
            short8 kB1 = *(short8*)&Ksg[(16 + col) * 72 + 32 + quad * 8];
            float4v sA = {0,0,0,0}, sB = {0,0,0,0};
            sA = __builtin_amdgcn_mfma_f32_16x16x32_bf16(qf0, kA0, sA, 0, 0, 0);
            sA = __builtin_amdgcn_mfma_f32_16x16x32_bf16(qf1, kA1, sA, 0, 0, 0);
            sB = __builtin_amdgcn_mfma_f32_16x16x32_bf16(qf0, kB0, sB, 0, 0, 0);
            sB = __builtin_amdgcn_mfma_f32_16x16x32_bf16(qf1, kB1, sB, 0, 0, 0);

            #pragma unroll
            for (int r = 0; r < 4; r++) {
                float pa = exp2f(sA[r] * SCALE2);
                float pb = exp2f(sB[r] * SCALE2);
                lst[r] += pa + pb;
                Ps[(w * 16 + quad * 4 + r) * 40 + col]      = f2bf(pa);
                Ps[(w * 16 + quad * 4 + r) * 40 + col + 16] = f2bf(pb);
            }
            asm volatile("s_waitcnt lgkmcnt(0)" ::: "memory");

            short8 pf  = *(short8*)&Ps[(w * 16 + col) * 40 + quad * 8];
            short8 vf0 = *(short8*)&Vtg[(col) * 40 + ((quad ^ ((col >> 3) & 3)) << 3)];
            short8 vf1 = *(short8*)&Vtg[(16 + col) * 40 + ((quad ^ (((16 + col) >> 3) & 3)) << 3)];
            short8 vf2 = *(short8*)&Vtg[(32 + col) * 40 + ((quad ^ (((32 + col) >> 3) & 3)) << 3)];
            short8 vf3 = *(short8*)&Vtg[(48 + col) * 40 + ((quad ^ (((48 + col) >> 3) & 3)) << 3)];
            O0 = __builtin_amdgcn_mfma_f32_16x16x32_bf16(pf, vf0, O0, 0, 0, 0);
            O1 = __builtin_amdgcn_mfma_f32_16x16x32_bf16(pf, vf1, O1, 0, 0, 0);
            O2 = __builtin_amdgcn_mfma_f32_16x16x32_bf16(pf, vf2, O2, 0, 0, 0);
            O3 = __builtin_amdgcn_mfma_f32_16x16x32_bf16(pf, vf3, O3, 0, 0, 0);
        }

        int sp = s * 2 + g;
        size_t base = ((size_t)(b * HH + h) * 16 + sp) * 32;
        #pragma unroll
        for (int r = 0; r < 4; r++) {
            float l = lst[r];
            #pragma unroll
            for (int mk = 1; mk < 16; mk <<= 1) l += __shfl_xor(l, mk);
            int q = qt * 16 + quad * 4 + r;
            if (col == 0) pl[base + q] = l;
            float* Od = pO + (base + q) * 64;
            Od[col]      = O0[r];
            Od[col + 16] = O1[r];
            Od[col + 32] = O2[r];
            Od[col + 48] = O3[r];
        }
    }
}

// ---------------- merge 16 partials per (b,h): plain sums ----------------
__global__ __launch_bounds__(256)
void global_merge(const float* __restrict__ pl, const float* __restrict__ pO,
                  const int* __restrict__ glist, const int* __restrict__ gcount,
                  short* __restrict__ ao) {
    int h = blockIdx.x, b = blockIdx.y;
    int t = threadIdx.x;
    int d = t & 63, qg = t >> 6;
    int nG = *gcount;
    size_t bh = ((size_t)(b * HH + h) * 16) * 32;

    for (int q = qg; q < nG; q += 4) {
        float L = 0.f, acc = 0.f;
        #pragma unroll
        for (int sp = 0; sp < 16; sp++) {
            L   += pl[bh + sp * 32 + q];
            acc += pO[(bh + sp * 32 + q) * 64 + d];
        }
        int i = glist[q];
        ao[((size_t)b * SS + i) * DMM + h * HDD + d] = f2bf(acc / L);
    }
}

extern "C" void kernel_launch(void* const* d_in, const int* in_sizes, int n_in,
                              void* d_out, int out_size, void* d_ws, size_t ws_size,
                              hipStream_t stream) {
    const float* q  = (const float*)d_in[0];
    const float* k  = (const float*)d_in[1];
    const float* v  = (const float*)d_in[2];
    const float* Wq = (const float*)d_in[3];
    const float* Wk = (const float*)d_in[4];
    const float* Wv = (const float*)d_in[5];
    const float* Wo = (const float*)d_in[6];
    const float* bq = (const float*)d_in[7];
    const float* bk = (const float*)d_in[8];
    const float* bv = (const float*)d_in[9];
    const float* bo = (const float*)d_in[10];
    const int* gidx = (const int*)d_in[11];
    float* out = (float*)d_out;

    // ws (64.03 MB): 32KB hdr | qh,kh,vh,ao bf16 8MB ea | wbf 8MB | abf 24MB (aliased by pl+pO)
    const size_t NE = (size_t)BB * SS * DMM;   // 4M
    const size_t WE = (size_t)DMM * DMM;       // 1M
    int*   g      = (int*)d_ws;
    int*   glist  = g + SS;
    int*   gcount = glist + SS;
    short* qh     = (short*)((char*)d_ws + 32768);
    short* kh     = qh + NE;
    short* vh     = kh + NE;
    short* ao     = vh + NE;
    short* wbf    = ao + NE;
    short* wo     = wbf + 3 * WE;
    short* abf    = wbf + 4 * WE;          // dead after QKV gemm
    float* pl     = (float*)abf;           // alias: written by attn_fused gpart branch (later)
    float* pO     = pl + 16384;

    dim3 gc(2048, 8);   // z=0..6 convert, z=7 fused setup_globals
    convert_all<<<gc, 256, 0, stream>>>(q, k, v, Wq, Wk, Wv, Wo, abf, wbf,
                                        gidx, g, glist, gcount);

    dim3 gq(64, 3);    // batched QKV, 256x256 tiles: 192 blocks, 512 threads
    gemm256<1, 1><<<gq, 512, 0, stream>>>(abf, wbf, bq, bk, bv, qh, kh, vh);

    attn_fused<<<1280, 256, 0, stream>>>(qh, kh, vh, glist, gcount, ao, pl, pO);

    dim3 gm(HH, BB);
    global_merge<<<gm, 256, 0, stream>>>(pl, pO, glist, gcount, ao);

    gemm128wo<<<256, 512, 0, stream>>>(ao, wo, bo, out);   // Wo: full CU coverage
}

// Round 6
// 208.398 us; speedup vs baseline: 1.1548x; 1.0344x over previous
//
#include <hip/hip_runtime.h>
#include <hip/hip_bf16.h>
#include <math.h>

#define BB 2
#define SS 2048
#define DMM 1024
#define HH 16
#define HDD 64
#define NGLOB 32
#define MM 4096   // B*S
#define SCALE2 0.18033688f   // 0.125 * log2(e): exp(s/8) == exp2(s*SCALE2)

typedef __attribute__((ext_vector_type(8))) short short8;
typedef __attribute__((ext_vector_type(4))) float float4v;

__device__ __forceinline__ short f2bf(float f) {
    union { float f; unsigned u; } x; x.f = f;
    unsigned r = (x.u + 0x7fffu + ((x.u >> 16) & 1u)) >> 16;  // RNE
    return (short)r;
}

// async 16B global->LDS (m97 path). LDS dest = wave-uniform base + lane*16.
#define ASYNC16(gp, lp) __builtin_amdgcn_global_load_lds( \
    (__attribute__((address_space(1))) void*)(gp), \
    (__attribute__((address_space(3))) void*)(lp), 16, 0, 0)

// Vt slot swizzle: key-chunk XORed with dim-derived tag -> breaks the
// dim*stride==0 (mod 32 banks) collapse on transpose stores (16-way -> 4-way).
#define VSL(dim, key) ((dim) * 40 + (((((key) >> 3) ^ (((dim) >> 3) & 3)) << 3) | ((key) & 7)))

// ---------------- convert fp32->bf16 (q,k,v,4 weights) + fused setup_globals (z==7) ----------------
__global__ __launch_bounds__(256)
void convert_all(const float* __restrict__ q, const float* __restrict__ k,
                 const float* __restrict__ v,
                 const float* __restrict__ w0, const float* __restrict__ w1,
                 const float* __restrict__ w2, const float* __restrict__ w3,
                 short* __restrict__ abf, short* __restrict__ wbf,
                 const int* __restrict__ gidx, int* __restrict__ g,
                 int* __restrict__ glist, int* __restrict__ gcount) {
    int z = blockIdx.y;
    int t = threadIdx.x;
    if (z == 7) {                      // fused setup_globals: 1 real block
        if (blockIdx.x != 0) return;
        for (int i = t; i < SS; i += 256) g[i] = 0;
        if (t == 0) *gcount = 0;
        __syncthreads();
        if (t < NGLOB) {
            int j = gidx[t];
            if (j >= 0 && j < SS) g[j] = 1;
        }
        __syncthreads();
        for (int j = t; j < SS; j += 256) {
            if (g[j]) {
                int p = atomicAdd(gcount, 1);
                glist[p] = j;
            }
        }
        return;
    }
    const float* src;
    short* dst;
    size_t n;
    if (z < 3) {
        src = (z == 0) ? q : (z == 1) ? k : v;
        dst = abf + (size_t)z * ((size_t)MM * DMM);
        n = (size_t)MM * DMM;
    } else {
        int y = z - 3;
        src = (y == 0) ? w0 : (y == 1) ? w1 : (y == 2) ? w2 : w3;
        dst = wbf + (size_t)y * ((size_t)DMM * DMM);
        n = (size_t)DMM * DMM;
    }
    size_t i = ((size_t)blockIdx.x * 256 + t) * 8;
    if (i >= n) return;
    float4 a = *(const float4*)(src + i);
    float4 b = *(const float4*)(src + i + 4);
    short8 s;
    s[0]=f2bf(a.x); s[1]=f2bf(a.y); s[2]=f2bf(a.z); s[3]=f2bf(a.w);
    s[4]=f2bf(b.x); s[5]=f2bf(b.y); s[6]=f2bf(b.z); s[7]=f2bf(b.w);
    *(short8*)(dst + i) = s;
}

// ---------------- 256x256/BK=64 MFMA GEMM: true 8-phase interleave (m201 port) ----------------
// 512 threads = 8 waves (2M x 4N), wave tile 128x64, acc[8][4]. LDS 128 KB (2 dbuf).
// Per K-step: 4 phases, each {ds_read A-subtile (+B at p0); issue 2 of next tile's 8
// stage loads; barrier; setprio(1) 16 MFMA setprio(0); counted vmcnt at p1/p3; barrier}.
// Issue order [W0,W1,W2,W3,A0,A2,A1,A3]. Certification points: end-p3 vmcnt(2) -> next
// step's W*+A0+A2 (idx 0..5) landed, 2 in flight; end-p1 vmcnt(4) -> this step's A1/A3
// landed, 4 newer in flight. NEVER drains mid-loop. Wave w reads only W-group (w&3)
// (idx<=3) and its A groups (g0: A0 p01 / A1 p23; g1: A2 p01 / A3 p23) - each need is
// barrier-certified before its phase. T2 XOR swizzle (verified R4: conflicts=0).
template<int OBF, int HEADSPLIT>
__global__ __launch_bounds__(512, 2)
void gemm256(const short* __restrict__ Abase, const short* __restrict__ Wbase,
             const float* __restrict__ b0, const float* __restrict__ b1,
             const float* __restrict__ b2,
             void* __restrict__ O0p, void* __restrict__ O1p, void* __restrict__ O2p) {
    __shared__ short As[2][256 * 64];   // 64 KB
    __shared__ short Ws[2][256 * 64];   // 64 KB

    int t = threadIdx.x;
    int z = blockIdx.y;
    const short* A    = Abase + (size_t)z * ((size_t)MM * DMM);
    const short* W    = Wbase + (size_t)z * ((size_t)DMM * DMM);
    const float* bias = (z == 0) ? b0 : (z == 1) ? b1 : b2;
    void* outp        = (z == 0) ? O0p : (z == 1) ? O1p : O2p;

    int bid = blockIdx.x;
    int mt = bid & 15, nt = bid >> 4;   // bid%8 == mt%8: nt-blocks of one mt share an XCD
    int m0 = mt * 256, n0 = nt * 256;

    int lane = t & 63, w = t >> 6;
    int quad = lane >> 4, col = lane & 15;
    int wm = (w >> 2) * 128;
    int wn = (w & 3) * 64;

    float4v acc[8][4];
    #pragma unroll
    for (int i = 0; i < 8; i++)
        #pragma unroll
        for (int j = 0; j < 4; j++) acc[i][j] = (float4v){0, 0, 0, 0};

    int srow = t >> 3;
    int scol = ((t & 7) ^ (srow & 7)) * 8;
    const short* Ap = A + (size_t)(m0 + srow) * DMM + scol;
    const short* Wp = W + (size_t)(n0 + srow) * DMM + scol;

    #define ST_W(bf, tt, h) ASYNC16(Wp + (size_t)(h) * 64 * DMM + (size_t)(tt) * 64, \
                                    &Ws[bf][(h) * 4096 + t * 8])
    #define ST_A(bf, tt, h) ASYNC16(Ap + (size_t)(h) * 64 * DMM + (size_t)(tt) * 64, \
                                    &As[bf][(h) * 4096 + t * 8])

    int c7 = col & 7;

    // prologue: stage step 0 in counted order, certify idx 0..5
    ST_W(0, 0, 0); ST_W(0, 0, 1); ST_W(0, 0, 2); ST_W(0, 0, 3);
    ST_A(0, 0, 0); ST_A(0, 0, 2); ST_A(0, 0, 1); ST_A(0, 0, 3);
    asm volatile("s_waitcnt vmcnt(2)" ::: "memory");
    __builtin_amdgcn_s_barrier();

    for (int it = 0; it < 16; it++) {
        int cur = it & 1, nb = cur ^ 1;
        bool pf = (it < 15);

        // B fragments for the whole K-step (wave's own W-group, certified idx<=3)
        short8 bF[4][2];
        #pragma unroll
        for (int j = 0; j < 4; j++) {
            int rB = (wn + 16 * j + col) * 64;
            #pragma unroll
            for (int ks = 0; ks < 2; ks++)
                bF[j][ks] = *(short8*)&Ws[cur][rB + ((((ks << 2) | quad) ^ c7) << 3)];
        }

        #pragma unroll
        for (int p = 0; p < 4; p++) {
            // ds_read this phase's A-subtile (wave rows 32p..32p+31)
            short8 aF[2][2];
            #pragma unroll
            for (int u = 0; u < 2; u++) {
                int rA = (wm + 16 * (2 * p + u) + col) * 64;
                #pragma unroll
                for (int ks = 0; ks < 2; ks++)
                    aF[u][ks] = *(short8*)&As[cur][rA + ((((ks << 2) | quad) ^ c7) << 3)];
            }
            // issue exactly 2 of next step's 8 stage loads
            if (pf) {
                if (p == 0)      { ST_W(nb, it + 1, 0); ST_W(nb, it + 1, 1); }
                else if (p == 1) { ST_W(nb, it + 1, 2); ST_W(nb, it + 1, 3); }
                else if (p == 2) { ST_A(nb, it + 1, 0); ST_A(nb, it + 1, 2); }
                else             { ST_A(nb, it + 1, 1); ST_A(nb, it + 1, 3); }
            }
            __builtin_amdgcn_s_barrier();
            __builtin_amdgcn_s_setprio(1);
            #pragma unroll
            for (int ks = 0; ks < 2; ks++)
                #pragma unroll
                for (int u = 0; u < 2; u++)
                    #pragma unroll
                    for (int j = 0; j < 4; j++)
                        acc[2 * p + u][j] = __builtin_amdgcn_mfma_f32_16x16x32_bf16(
                            aF[u][ks], bF[j][ks], acc[2 * p + u][j], 0, 0, 0);
            __builtin_amdgcn_s_setprio(0);
            // counted certification points (never drain mid-loop)
            if (p == 1) {
                if (pf) asm volatile("s_waitcnt vmcnt(4)" ::: "memory");  // this step's A1/A3 landed
                else    asm volatile("s_waitcnt vmcnt(0)" ::: "memory");  // tail: drain stragglers
            }
            if (p == 3 && pf)
                asm volatile("s_waitcnt vmcnt(2)" ::: "memory");          // next step idx 0..5 landed
            __builtin_amdgcn_s_barrier();
        }
    }
    #undef ST_W
    #undef ST_A

    #pragma unroll
    for (int i = 0; i < 8; i++) {
        #pragma unroll
        for (int j = 0; j < 4; j++) {
            int n = n0 + wn + 16 * j + col;
            float bn = bias[n];
            #pragma unroll
            for (int r = 0; r < 4; r++) {
                int m = m0 + wm + 16 * i + quad * 4 + r;
                float val = acc[i][j][r] + bn;
                size_t idx;
                if (HEADSPLIT) {
                    int b = m >> 11;
                    int s = m & 2047;
                    int h = n >> 6;
                    int hd = n & 63;
                    idx = (((size_t)b * HH + h) * SS + s) * HDD + hd;
                } else {
                    idx = (size_t)m * DMM + n;
                }
                if (OBF) ((short*)outp)[idx] = f2bf(val);
                else     ((float*)outp)[idx] = val;
            }
        }
    }
}

// ---------------- Wo GEMM: 128x128/BK=64, 512 thr, T2 swizzle + counted vmcnt + T5 --------------
// 256 blocks = full CU coverage. Same verified swizzle/pipeline algebra as gemm256 (R4/R5).
__global__ __launch_bounds__(512, 2)
void gemm128wo(const short* __restrict__ A, const short* __restrict__ W,
               const float* __restrict__ bias, float* __restrict__ out) {
    __shared__ short As[2][128 * 64];   // 32 KB
    __shared__ short Ws[2][128 * 64];   // 32 KB

    int t = threadIdx.x;
    int bid = blockIdx.x;
    int mt = bid & 31, nt = bid >> 5;   // bid%8 == mt%8: nt-blocks of one mt share an XCD
    int m0 = mt * 128, n0 = nt * 128;

    int lane = t & 63, w = t >> 6;
    int quad = lane >> 4, col = lane & 15;
    int wm = (w >> 2) * 64;    // 2 wave-rows
    int wn = (w & 3) * 32;     // 4 wave-cols

    float4v acc[4][2];
    #pragma unroll
    for (int i = 0; i < 4; i++)
        #pragma unroll
        for (int j = 0; j < 2; j++) acc[i][j] = (float4v){0, 0, 0, 0};

    int srow = t >> 3;                       // 0..63
    int scol = ((t & 7) ^ (srow & 7)) * 8;   // pre-swizzled source column
    const short* Ap = A + (size_t)(m0 + srow) * DMM + scol;
    const short* Wp = W + (size_t)(n0 + srow) * DMM + scol;

    #define STAGEWO(bf, tt) do { size_t kk = (size_t)(tt) * 64; \
        ASYNC16(Ap + kk,                      &As[bf][t * 8]); \
        ASYNC16(Ap + 64 * (size_t)DMM + kk,   &As[bf][4096 + t * 8]); \
        ASYNC16(Wp + kk,                      &Ws[bf][t * 8]); \
        ASYNC16(Wp + 64 * (size_t)DMM + kk,   &Ws[bf][4096 + t * 8]); \
    } while (0)

    int c7 = col & 7;

    STAGEWO(0, 0);

    for (int it = 0; it < 16; it++) {
        int cur = it & 1;
        if (it < 15) {
            STAGEWO(cur ^ 1, it + 1);
            asm volatile("s_waitcnt vmcnt(4)" ::: "memory");   // current tile's 4 landed
        } else {
            asm volatile("s_waitcnt vmcnt(0)" ::: "memory");
        }
        __builtin_amdgcn_s_barrier();

        short8 bF[2][2];
        #pragma unroll
        for (int j = 0; j < 2; j++) {
            int rB = (wn + 16 * j + col) * 64;
            #pragma unroll
            for (int ks = 0; ks < 2; ks++)
                bF[j][ks] = *(short8*)&Ws[cur][rB + ((((ks << 2) | quad) ^ c7) << 3)];
        }

        #pragma unroll
        for (int p = 0; p < 2; p++) {
            if (p) __builtin_amdgcn_s_barrier();
            short8 aF[2][2];
            #pragma unroll
            for (int u = 0; u < 2; u++) {
                int rA = (wm + 16 * (2 * p + u) + col) * 64;
                #pragma unroll
                for (int ks = 0; ks < 2; ks++)
                    aF[u][ks] = *(short8*)&As[cur][rA + ((((ks << 2) | quad) ^ c7) << 3)];
            }
            __builtin_amdgcn_s_setprio(1);
            #pragma unroll
            for (int ks = 0; ks < 2; ks++)
                #pragma unroll
                for (int u = 0; u < 2; u++)
                    #pragma unroll
                    for (int j = 0; j < 2; j++)
                        acc[2 * p + u][j] = __builtin_amdgcn_mfma_f32_16x16x32_bf16(
                            aF[u][ks], bF[j][ks], acc[2 * p + u][j], 0, 0, 0);
            __builtin_amdgcn_s_setprio(0);
        }
        __builtin_amdgcn_s_barrier();
    }
    #undef STAGEWO

    #pragma unroll
    for (int i = 0; i < 4; i++) {
        #pragma unroll
        for (int j = 0; j < 2; j++) {
            int n = n0 + wn + 16 * j + col;
            float bn = bias[n];
            #pragma unroll
            for (int r = 0; r < 4; r++) {
                int m = m0 + wm + 16 * i + quad * 4 + r;
                out[(size_t)m * DMM + n] = acc[i][j][r] + bn;
            }
        }
    }
}

// ---------------- fused attention: band (blocks 0..1023) + global_part (1024..1279) ----------------
__global__ __launch_bounds__(256)
void attn_fused(const short* __restrict__ qh, const short* __restrict__ kh,
                const short* __restrict__ vh, const int* __restrict__ glist,
                const int* __restrict__ gcount, short* __restrict__ ao,
                float* __restrict__ pl, float* __restrict__ pO) {
    __shared__ __align__(16) char smem[29184];
    int t = threadIdx.x;
    int bid = blockIdx.x;
    int nG = *gcount;

    if (bid < 1024) {
        // ---------- banded attention (XCD-local, swizzled Vt, interval mask, T14 prefetch) -------
        short* Qs = (short*)smem;            // 64*72
        short* Ks = Qs + 64 * 72;            // 32*72
        short* Vt = Ks + 32 * 72;            // 64*40
        short* Ps = Vt + 64 * 40;            // 4*16*40
        int*   gjs = (int*)(Ps + 4 * 16 * 40);  // 32 ints

        int xcd = bid & 7, idx = bid >> 3;
        int gl  = idx >> 4;
        int qt  = idx & 15;
        int gid = xcd * 8 + gl;
        int z   = gid >> 4;
        int h   = gid & 15;
        int b = z >> 1, p = z & 1;
        int qq0 = qt * 64;

        const short* Qb = qh + ((size_t)(b * HH + h) * SS) * HDD;
        const short* Kb = kh + ((size_t)(b * HH + h) * SS) * HDD;
        const short* Vb = vh + ((size_t)(b * HH + h) * SS) * HDD;

        int row8 = t >> 3;
        int dim8 = (t & 7) * 8;

        #pragma unroll
        for (int rr = 0; rr < 2; rr++) {
            int row = rr * 32 + row8;
            int i = 2 * (qq0 + row) + p;
            short8 qv = *(const short8*)(Qb + (size_t)i * HDD + dim8);
            *(short8*)&Qs[row * 72 + dim8] = qv;
        }
        if (t < 32) gjs[t] = (t < nG) ? glist[t] : -1000000;
        __syncthreads();

        int lane = t & 63, w = t >> 6;
        int quad = lane >> 4, col = lane & 15;

        short8 qf0 = *(short8*)&Qs[(16 * w + col) * 72 + quad * 8];
        short8 qf1 = *(short8*)&Qs[(16 * w + col) * 72 + 32 + quad * 8];

        float4v O0 = {0,0,0,0}, O1 = {0,0,0,0}, O2 = {0,0,0,0}, O3 = {0,0,0,0};
        float lst[4] = {0.f, 0.f, 0.f, 0.f};

        short8 kvP, vvP, kvN, vvN;
        {
            int srow = 2 * (qq0 - 256 + row8) + p;
            srow = srow < 0 ? 0 : (srow > SS - 1 ? SS - 1 : srow);
            kvP = *(const short8*)(Kb + (size_t)srow * HDD + dim8);
            vvP = *(const short8*)(Vb + (size_t)srow * HDD + dim8);
        }

        for (int c = 0; c < 19; c++) {
            __syncthreads();
            *(short8*)&Ks[row8 * 72 + dim8] = kvP;
            #pragma unroll
            for (int j = 0; j < 8; j++) {
                int d = dim8 + j;
                Vt[VSL(d, row8)] = vvP[j];
            }
            if (c < 18) {
                int cn = c + 1;
                int ch0n = qq0 - 256 + cn * 32;
                int srow;
                if (cn < 18) srow = 2 * (ch0n + row8) + p;
                else         srow = (row8 < nG) ? gjs[row8] : 0;
                srow = srow < 0 ? 0 : (srow > SS - 1 ? SS - 1 : srow);
                kvN = *(const short8*)(Kb + (size_t)srow * HDD + dim8);
                vvN = *(const short8*)(Vb + (size_t)srow * HDD + dim8);
            }
            __syncthreads();

            int ch0 = qq0 - 256 + c * 32;

            short8 kA0 = *(short8*)&Ks[col * 72 + quad * 8];
            short8 kA1 = *(short8*)&Ks[col * 72 + 32 + quad * 8];
            short8 kB0 = *(short8*)&Ks[(16 + col) * 72 + quad * 8];
            short8 kB1 = *(short8*)&Ks[(16 + col) * 72 + 32 + quad * 8];
            float4v sA = {0,0,0,0}, sB = {0,0,0,0};
            sA = __builtin_amdgcn_mfma_f32_16x16x32_bf16(qf0, kA0, sA, 0, 0, 0);
            sA = __builtin_amdgcn_mfma_f32_16x16x32_bf16(qf1, kA1, sA, 0, 0, 0);
            sB = __builtin_amdgcn_mfma_f32_16x16x32_bf16(qf0, kB0, sB, 0, 0, 0);
            sB = __builtin_amdgcn_mfma_f32_16x16x32_bf16(qf1, kB1, sB, 0, 0, 0);

            if (c < 18) {
                int nlo = -ch0;
                int nhi = 1023 - ch0;
                #pragma unroll
                for (int r = 0; r < 4; r++) {
                    int qq = qq0 + 16 * w + quad * 4 + r;
                    int u  = qq - ch0;
                    int lo = max(u - 256, nlo);
                    int hi = min(u + 256, nhi);
                    bool vA = (col >= lo) && (col <= hi);
                    bool vB = (col + 16 >= lo) && (col + 16 <= hi);
                    float pa = vA ? exp2f(sA[r] * SCALE2) : 0.f;
                    float pb = vB ? exp2f(sB[r] * SCALE2) : 0.f;
                    lst[r] += pa + pb;
                    Ps[(w * 16 + quad * 4 + r) * 40 + col]      = f2bf(pa);
                    Ps[(w * 16 + quad * 4 + r) * 40 + col + 16] = f2bf(pb);
                }
            } else {
                #pragma unroll
                for (int r = 0; r < 4; r++) {
                    int qq = qq0 + 16 * w + quad * 4 + r;
                    int i = 2 * qq + p;
                    int jA = gjs[col], jB = gjs[col + 16];
                    int dA = jA - i, dB = jB - i;
                    int aA = dA < 0 ? -dA : dA;
                    int aB = dB < 0 ? -dB : dB;
                    bool vA = (jA >= 0) && !((aA <= 512) && ((dA & 1) == 0));
                    bool vB = (jB >= 0) && !((aB <= 512) && ((dB & 1) == 0));
                    float pa = vA ? exp2f(sA[r] * SCALE2) : 0.f;
                    float pb = vB ? exp2f(sB[r] * SCALE2) : 0.f;
                    lst[r] += pa + pb;
                    Ps[(w * 16 + quad * 4 + r) * 40 + col]      = f2bf(pa);
                    Ps[(w * 16 + quad * 4 + r) * 40 + col + 16] = f2bf(pb);
                }
            }
            asm volatile("s_waitcnt lgkmcnt(0)" ::: "memory");

            short8 pf  = *(short8*)&Ps[(w * 16 + col) * 40 + quad * 8];
            short8 vf0 = *(short8*)&Vt[(col) * 40 + ((quad ^ ((col >> 3) & 3)) << 3)];
            short8 vf1 = *(short8*)&Vt[(16 + col) * 40 + ((quad ^ (((16 + col) >> 3) & 3)) << 3)];
            short8 vf2 = *(short8*)&Vt[(32 + col) * 40 + ((quad ^ (((32 + col) >> 3) & 3)) << 3)];
            short8 vf3 = *(short8*)&Vt[(48 + col) * 40 + ((quad ^ (((48 + col) >> 3) & 3)) << 3)];
            O0 = __builtin_amdgcn_mfma_f32_16x16x32_bf16(pf, vf0, O0, 0, 0, 0);
            O1 = __builtin_amdgcn_mfma_f32_16x16x32_bf16(pf, vf1, O1, 0, 0, 0);
            O2 = __builtin_amdgcn_mfma_f32_16x16x32_bf16(pf, vf2, O2, 0, 0, 0);
            O3 = __builtin_amdgcn_mfma_f32_16x16x32_bf16(pf, vf3, O3, 0, 0, 0);

            kvP = kvN; vvP = vvN;
        }

        #pragma unroll
        for (int r = 0; r < 4; r++) {
            float l = lst[r];
            #pragma unroll
            for (int mk = 1; mk < 16; mk <<= 1) l += __shfl_xor(l, mk);
            float inv = 1.0f / l;
            int q = 16 * w + quad * 4 + r;
            int i = 2 * (qq0 + q) + p;
            short* dst = ao + ((size_t)b * SS + i) * DMM + h * HDD;
            dst[col]      = f2bf(O0[r] * inv);
            dst[col + 16] = f2bf(O1[r] * inv);
            dst[col + 32] = f2bf(O2[r] * inv);
            dst[col + 48] = f2bf(O3[r] * inv);
        }
    } else {
        // ---------- global rows: split-K MFMA partials (no-max softmax) ----------
        short* Qs  = (short*)smem;            // 32*72
        short* Ksf = Qs + 32 * 72;            // 2 x 32*72
        short* Vtf = Ksf + 2 * 32 * 72;       // 2 x 64*40
        short* Ps  = Vtf + 2 * 64 * 40;       // 4*16*40

        int r0 = bid - 1024;
        int s = r0 & 7, h = (r0 >> 3) & 15, b = r0 >> 7;

        const short* Qb = qh + ((size_t)(b * HH + h) * SS) * HDD;
        const short* Kb = kh + ((size_t)(b * HH + h) * SS) * HDD;
        const short* Vb = vh + ((size_t)(b * HH + h) * SS) * HDD;

        int row8 = t >> 3, dim8 = (t & 7) * 8;
        {
            int cq = row8 < nG ? row8 : 0;
            int src = glist[cq];
            short8 qv = *(const short8*)(Qb + (size_t)src * HDD + dim8);
            *(short8*)&Qs[row8 * 72 + dim8] = qv;
        }
        __syncthreads();

        int lane = t & 63, w = t >> 6;
        int quad = lane >> 4, col = lane & 15;
        int g = w >> 1, qt = w & 1;

        short8 qf0 = *(short8*)&Qs[(qt * 16 + col) * 72 + quad * 8];
        short8 qf1 = *(short8*)&Qs[(qt * 16 + col) * 72 + 32 + quad * 8];

        float4v O0 = {0,0,0,0}, O1 = {0,0,0,0}, O2 = {0,0,0,0}, O3 = {0,0,0,0};
        float lst[4] = {0.f, 0.f, 0.f, 0.f};

        int js0 = s * 256;
        for (int it = 0; it < 4; it++) {
            __syncthreads();
            int r64 = t >> 2, dimb = (t & 3) * 16;
            int j = js0 + it * 64 + r64;
            const short* kp = Kb + (size_t)j * HDD + dimb;
            const short* vp = Vb + (size_t)j * HDD + dimb;
            short8 k0 = *(const short8*)kp, k1 = *(const short8*)(kp + 8);
            short8 v0 = *(const short8*)vp, v1 = *(const short8*)(vp + 8);
            int half = r64 >> 5, r32 = r64 & 31;
            short* Ksh = Ksf + half * (32 * 72);
            short* Vth = Vtf + half * (64 * 40);
            *(short8*)&Ksh[r32 * 72 + dimb]     = k0;
            *(short8*)&Ksh[r32 * 72 + dimb + 8] = k1;
            #pragma unroll
            for (int u = 0; u < 8; u++) {
                int d = dimb + u;
                Vth[VSL(d, r32)] = v0[u];
            }
            #pragma unroll
            for (int u = 0; u < 8; u++) {
                int d = dimb + 8 + u;
                Vth[VSL(d, r32)] = v1[u];
            }
            __syncthreads();

            short* Ksg = Ksf + g * (32 * 72);
            short* Vtg = Vtf + g * (64 * 40);
            short8 kA0 = *(short8*)&Ksg[col * 72 + quad * 8];
            short8 kA1 = *(short8*)&Ksg[col * 72 + 32 + quad * 8];
            short8 kB0 = *(short8*)&Ksg[(16 + col) * 72 + quad * 8];
            short8 kB1 = *(short8*)&Ksg[(16 + col) * 72 + 32 + quad * 8];
            float4v sA = {0,0,0,0}, sB = {0,0,0,0};
            sA = __builtin_amdgcn_mfma_f32_16x16x32_bf16(qf0, kA0, sA, 0, 0, 0);
            sA = __builtin_amdgcn_mfma_f32_16x16x32_bf16(qf1, kA1, sA, 0, 0, 0);
            sB = __builtin_amdgcn_mfma_f32_16x16x32_bf16(qf0, kB0, sB, 0, 0, 0);
            sB = __builtin_amdgcn_mfma_f32_16x16x32_bf16(qf1, kB1, sB, 0, 0, 0);

            #pragma unroll
            for (int r = 0; r < 4; r++) {
                float pa = exp2f(sA[r] * SCALE2);
                float pb = exp2f(sB[r] * SCALE2);
                lst[r] += pa + pb;
                Ps[(w * 16 + quad * 4 + r) * 40 + col]      = f2bf(pa);
                Ps[(w * 16 + quad * 4 + r) * 40 + col + 16] = f2bf(pb);
            }
            asm volatile("s_waitcnt lgkmcnt(0)" ::: "memory");

            short8 pf  = *(short8*)&Ps[(w * 16 + col) * 40 + quad * 8];
            short8 vf0 = *(short8*)&Vtg[(col) * 40 + ((quad ^ ((col >> 3) & 3)) << 3)];
            short8 vf1 = *(short8*)&Vtg[(16 + col) * 40 + ((quad ^ (((16 + col) >> 3) & 3)) << 3)];
            short8 vf2 = *(short8*)&Vtg[(32 + col) * 40 + ((quad ^ (((32 + col) >> 3) & 3)) << 3)];
            short8 vf3 = *(short8*)&Vtg[(48 + col) * 40 + ((quad ^ (((48 + col) >> 3) & 3)) << 3)];
            O0 = __builtin_amdgcn_mfma_f32_16x16x32_bf16(pf, vf0, O0, 0, 0, 0);
            O1 = __builtin_amdgcn_mfma_f32_16x16x32_bf16(pf, vf1, O1, 0, 0, 0);
            O2 = __builtin_amdgcn_mfma_f32_16x16x32_bf16(pf, vf2, O2, 0, 0, 0);
            O3 = __builtin_amdgcn_mfma_f32_16x16x32_bf16(pf, vf3, O3, 0, 0, 0);
        }

        int sp = s * 2 + g;
        size_t base = ((size_t)(b * HH + h) * 16 + sp) * 32;
        #pragma unroll
        for (int r = 0; r < 4; r++) {
            float l = lst[r];
            #pragma unroll
            for (int mk = 1; mk < 16; mk <<= 1) l += __shfl_xor(l, mk);
            int q = qt * 16 + quad * 4 + r;
            if (col == 0) pl[base + q] = l;
            float* Od = pO + (base + q) * 64;
            Od[col]      = O0[r];
            Od[col + 16] = O1[r];
            Od[col + 32] = O2[r];
            Od[col + 48] = O3[r];
        }
    }
}

// ---------------- merge 16 partials per (b,h): plain sums ----------------
__global__ __launch_bounds__(256)
void global_merge(const float* __restrict__ pl, const float* __restrict__ pO,
                  const int* __restrict__ glist, const int* __restrict__ gcount,
                  short* __restrict__ ao) {
    int h = blockIdx.x, b = blockIdx.y;
    int t = threadIdx.x;
    int d = t & 63, qg = t >> 6;
    int nG = *gcount;
    size_t bh = ((size_t)(b * HH + h) * 16) * 32;

    for (int q = qg; q < nG; q += 4) {
        float L = 0.f, acc = 0.f;
        #pragma unroll
        for (int sp = 0; sp < 16; sp++) {
            L   += pl[bh + sp * 32 + q];
            acc += pO[(bh + sp * 32 + q) * 64 + d];
        }
        int i = glist[q];
        ao[((size_t)b * SS + i) * DMM + h * HDD + d] = f2bf(acc / L);
    }
}

extern "C" void kernel_launch(void* const* d_in, const int* in_sizes, int n_in,
                              void* d_out, int out_size, void* d_ws, size_t ws_size,
                              hipStream_t stream) {
    const float* q  = (const float*)d_in[0];
    const float* k  = (const float*)d_in[1];
    const float* v  = (const float*)d_in[2];
    const float* Wq = (const float*)d_in[3];
    const float* Wk = (const float*)d_in[4];
    const float* Wv = (const float*)d_in[5];
    const float* Wo = (const float*)d_in[6];
    const float* bq = (const float*)d_in[7];
    const float* bk = (const float*)d_in[8];
    const float* bv = (const float*)d_in[9];
    const float* bo = (const float*)d_in[10];
    const int* gidx = (const int*)d_in[11];
    float* out = (float*)d_out;

    // ws (64.03 MB): 32KB hdr | qh,kh,vh,ao bf16 8MB ea | wbf 8MB | abf 24MB (aliased by pl+pO)
    const size_t NE = (size_t)BB * SS * DMM;   // 4M
    const size_t WE = (size_t)DMM * DMM;       // 1M
    int*   g      = (int*)d_ws;
    int*   glist  = g + SS;
    int*   gcount = glist + SS;
    short* qh     = (short*)((char*)d_ws + 32768);
    short* kh     = qh + NE;
    short* vh     = kh + NE;
    short* ao     = vh + NE;
    short* wbf    = ao + NE;
    short* wo     = wbf + 3 * WE;
    short* abf    = wbf + 4 * WE;          // dead after QKV gemm
    float* pl     = (float*)abf;           // alias: written by attn_fused gpart branch (later)
    float* pO     = pl + 16384;

    dim3 gc(2048, 8);   // z=0..6 convert, z=7 fused setup_globals
    convert_all<<<gc, 256, 0, stream>>>(q, k, v, Wq, Wk, Wv, Wo, abf, wbf,
                                        gidx, g, glist, gcount);

    dim3 gq(64, 3);    // batched QKV, 256x256 tiles: 192 blocks, 512 threads
    gemm256<1, 1><<<gq, 512, 0, stream>>>(abf, wbf, bq, bk, bv, qh, kh, vh);

    attn_fused<<<1280, 256, 0, stream>>>(qh, kh, vh, glist, gcount, ao, pl, pO);

    dim3 gm(HH, BB);
    global_merge<<<gm, 256, 0, stream>>>(pl, pO, glist, gcount, ao);

    gemm128wo<<<256, 512, 0, stream>>>(ao, wo, bo, out);   // Wo: full CU coverage
}